// Round 1
// baseline (636.239 us; speedup 1.0000x reference)
//
#include <hip/hip_runtime.h>
#include <math.h>

#define NHEAD 4
#define HDIM 32
#define NEG_SLOPE 0.1f

// ---------------- CSR build ----------------

__global__ void hist_k(const int* __restrict__ dst, int* __restrict__ cnt, int E) {
    int e = blockIdx.x * 256 + threadIdx.x;
    if (e < E) atomicAdd(&cnt[dst[e]], 1);
}

__global__ void scan1_k(const int* __restrict__ cnt, int* __restrict__ row_ptr,
                        int* __restrict__ bsum, int N) {
    __shared__ int s[256];
    int t = threadIdx.x;
    int i = blockIdx.x * 256 + t;
    int v = (i < N) ? cnt[i] : 0;
    s[t] = v;
    __syncthreads();
    int incl = v;
    for (int off = 1; off < 256; off <<= 1) {
        int add = (t >= off) ? s[t - off] : 0;
        __syncthreads();
        incl += add;
        s[t] = incl;
        __syncthreads();
    }
    if (i < N) row_ptr[i] = incl - v;  // exclusive within block
    if (t == 255) bsum[blockIdx.x] = incl;
}

__global__ void scan2_k(const int* __restrict__ bsum, int* __restrict__ boff, int nb) {
    __shared__ int s[256];
    int t = threadIdx.x;
    int v = (t < nb) ? bsum[t] : 0;
    s[t] = v;
    __syncthreads();
    int incl = v;
    for (int off = 1; off < 256; off <<= 1) {
        int add = (t >= off) ? s[t - off] : 0;
        __syncthreads();
        incl += add;
        s[t] = incl;
        __syncthreads();
    }
    boff[t] = incl - v;  // exclusive block offsets
}

__global__ void scan3_k(int* __restrict__ row_ptr, const int* __restrict__ boff,
                        int N, int E) {
    int i = blockIdx.x * 256 + threadIdx.x;
    if (i < N) row_ptr[i] += boff[i >> 8];
    if (i == 0) row_ptr[N] = E;
}

__global__ void scatter_k(const int* __restrict__ dst, const int* __restrict__ row_ptr,
                          int* __restrict__ fill, int* __restrict__ csr, int E) {
    int e = blockIdx.x * 256 + threadIdx.x;
    if (e >= E) return;
    int d = dst[e];
    int p = atomicAdd(&fill[d], 1);
    csr[row_ptr[d] + p] = e;
}

// ---------------- fp32 register-tiled GEMM: C[M,128] = A[M,K](lda) @ B[K,128] (+bias) ----------------
// block 256 threads, tile 64x128, BK=32. Each thread: 8 rows x 4 cols.

__global__ __launch_bounds__(256) void gemm_k(const float* __restrict__ A, int lda,
                                              const float* __restrict__ B,
                                              const float* __restrict__ bias,
                                              float* __restrict__ C, int M, int K) {
    __shared__ float As[64 * 36];    // 64 rows x 32 k, padded stride 36 (16B aligned)
    __shared__ float4 Bs[32 * 32];   // 32 k x 128 cols as float4

    int tid = threadIdx.x;
    int tn = tid & 31;   // col group: cols 4*tn..4*tn+3
    int tm = tid >> 5;   // row group 0..7: rows tm + 8*i
    int row0 = blockIdx.x * 64;

    float4 acc[8];
#pragma unroll
    for (int i = 0; i < 8; i++) acc[i] = make_float4(0.f, 0.f, 0.f, 0.f);

    for (int k0 = 0; k0 < K; k0 += 32) {
        // stage A tile: 64x32 floats = 512 float4, 2 per thread
#pragma unroll
        for (int t = 0; t < 2; t++) {
            int idx = tid + t * 256;          // 0..511
            int r = idx >> 3, c4 = idx & 7;
            float4 v = make_float4(0.f, 0.f, 0.f, 0.f);
            int row = row0 + r;
            if (row < M) v = *(const float4*)&A[(size_t)row * lda + k0 + c4 * 4];
            *(float4*)&As[r * 36 + c4 * 4] = v;
        }
        // stage B tile: 32x128 floats = 1024 float4, 4 per thread
#pragma unroll
        for (int t = 0; t < 4; t++) {
            int idx = tid + t * 256;          // 0..1023, = r*32 + c4
            int r = idx >> 5, c4 = idx & 31;
            Bs[idx] = ((const float4*)B)[(size_t)(k0 + r) * 32 + c4];
        }
        __syncthreads();

#pragma unroll
        for (int kk4 = 0; kk4 < 8; kk4++) {
            float4 b0 = Bs[(kk4 * 4 + 0) * 32 + tn];
            float4 b1 = Bs[(kk4 * 4 + 1) * 32 + tn];
            float4 b2 = Bs[(kk4 * 4 + 2) * 32 + tn];
            float4 b3 = Bs[(kk4 * 4 + 3) * 32 + tn];
#pragma unroll
            for (int i = 0; i < 8; i++) {
                float4 a = *(const float4*)&As[(tm + i * 8) * 36 + kk4 * 4];
                acc[i].x += a.x * b0.x + a.y * b1.x + a.z * b2.x + a.w * b3.x;
                acc[i].y += a.x * b0.y + a.y * b1.y + a.z * b2.y + a.w * b3.y;
                acc[i].z += a.x * b0.z + a.y * b1.z + a.z * b2.z + a.w * b3.z;
                acc[i].w += a.x * b0.w + a.y * b1.w + a.z * b2.w + a.w * b3.w;
            }
        }
        __syncthreads();
    }

#pragma unroll
    for (int i = 0; i < 8; i++) {
        int row = row0 + tm + i * 8;
        if (row < M) {
            float4 v = acc[i];
            if (bias) {
                float4 bv = ((const float4*)bias)[tn];
                v.x += bv.x; v.y += bv.y; v.z += bv.z; v.w += bv.w;
            }
            ((float4*)C)[(size_t)row * 32 + tn] = v;
        }
    }
}

// ---------------- per-node attention logits: el/er[n,h] = sum_d ft[n,h,d]*a{l,r}[h,d] ----------------
// one wave per node; lane j covers dims j and j+64.

__global__ __launch_bounds__(256) void elr_k(const float* __restrict__ ft,
                                             const float* __restrict__ al,
                                             const float* __restrict__ ar,
                                             float* __restrict__ el, float* __restrict__ er,
                                             int N) {
    int n = blockIdx.x * 4 + (threadIdx.x >> 6);
    if (n >= N) return;
    int lane = threadIdx.x & 63;
    float f0 = ft[(size_t)n * 128 + lane];
    float f1 = ft[(size_t)n * 128 + 64 + lane];
    float e0 = f0 * al[lane], e1 = f1 * al[64 + lane];
    float r0 = f0 * ar[lane], r1 = f1 * ar[64 + lane];
    // reduce within each 32-lane group (masks <= 16 keep within groups)
    for (int m = 16; m >= 1; m >>= 1) {
        e0 += __shfl_xor(e0, m);
        e1 += __shfl_xor(e1, m);
        r0 += __shfl_xor(r0, m);
        r1 += __shfl_xor(r1, m);
    }
    // lane 0: heads 0 (from j=0..31) and 2 (j=64..95); lane 32: heads 1 and 3
    if (lane == 0) {
        el[n * 4 + 0] = e0; el[n * 4 + 2] = e1;
        er[n * 4 + 0] = r0; er[n * 4 + 2] = r1;
    } else if (lane == 32) {
        el[n * 4 + 1] = e0; el[n * 4 + 3] = e1;
        er[n * 4 + 1] = r0; er[n * 4 + 3] = r1;
    }
}

// ---------------- per-edge logits: logit[e,h] = w[e] * leaky_relu(el[src,h] + er[dst,h]) ----------------

__global__ void elog_k(const float4* __restrict__ el4, const float4* __restrict__ er4,
                       const int* __restrict__ src, const int* __restrict__ dst,
                       const float* __restrict__ w, float4* __restrict__ logit, int E) {
    int e = blockIdx.x * 256 + threadIdx.x;
    if (e >= E) return;
    float4 a = el4[src[e]];
    float4 b = er4[dst[e]];
    float we = w[e];
    float4 l;
    l.x = a.x + b.x; l.x = we * (l.x > 0.f ? l.x : NEG_SLOPE * l.x);
    l.y = a.y + b.y; l.y = we * (l.y > 0.f ? l.y : NEG_SLOPE * l.y);
    l.z = a.z + b.z; l.z = we * (l.z > 0.f ? l.z : NEG_SLOPE * l.z);
    l.w = a.w + b.w; l.w = we * (l.w > 0.f ? l.w : NEG_SLOPE * l.w);
    logit[e] = l;
}

// ---------------- softmax + aggregation, gather-style: one wave per dst node ----------------
// out[n, ooff + j] = relu( sum_e softmax(logit)[e, head(j)] * ft[src_e, j] )

__global__ __launch_bounds__(256) void agg_k(const float* __restrict__ ft,
                                             const float4* __restrict__ logit,
                                             const int* __restrict__ csr,
                                             const int* __restrict__ row_ptr,
                                             const int* __restrict__ src,
                                             float* __restrict__ out, int ostride, int ooff,
                                             int N) {
    int n = blockIdx.x * 4 + (threadIdx.x >> 6);
    if (n >= N) return;
    int lane = threadIdx.x & 63;
    int r0 = row_ptr[n], r1 = row_ptr[n + 1];
    int deg = r1 - r0;
    float* op = out + (size_t)n * ostride + ooff;
    if (deg == 0) {
        op[lane] = 0.f;
        op[lane + 64] = 0.f;
        return;
    }
    // pass A: per-head max over incoming edges
    float4 mx = make_float4(-INFINITY, -INFINITY, -INFINITY, -INFINITY);
    for (int i = lane; i < deg; i += 64) {
        float4 l = logit[csr[r0 + i]];
        mx.x = fmaxf(mx.x, l.x); mx.y = fmaxf(mx.y, l.y);
        mx.z = fmaxf(mx.z, l.z); mx.w = fmaxf(mx.w, l.w);
    }
    for (int m = 32; m >= 1; m >>= 1) {
        mx.x = fmaxf(mx.x, __shfl_xor(mx.x, m));
        mx.y = fmaxf(mx.y, __shfl_xor(mx.y, m));
        mx.z = fmaxf(mx.z, __shfl_xor(mx.z, m));
        mx.w = fmaxf(mx.w, __shfl_xor(mx.w, m));
    }
    // pass B: per-head sum of exp
    float4 sm = make_float4(0.f, 0.f, 0.f, 0.f);
    for (int i = lane; i < deg; i += 64) {
        float4 l = logit[csr[r0 + i]];
        sm.x += __expf(l.x - mx.x); sm.y += __expf(l.y - mx.y);
        sm.z += __expf(l.z - mx.z); sm.w += __expf(l.w - mx.w);
    }
    for (int m = 32; m >= 1; m >>= 1) {
        sm.x += __shfl_xor(sm.x, m);
        sm.y += __shfl_xor(sm.y, m);
        sm.z += __shfl_xor(sm.z, m);
        sm.w += __shfl_xor(sm.w, m);
    }
    float4 inv;
    inv.x = 1.f / sm.x; inv.y = 1.f / sm.y; inv.z = 1.f / sm.z; inv.w = 1.f / sm.w;

    // pass C: wave-uniform loop over edges; lanes cover the 128 feature dims
    float acc0 = 0.f, acc1 = 0.f;
    for (int i = 0; i < deg; i++) {
        int eid = csr[r0 + i];
        float4 l = logit[eid];
        float4 a;
        a.x = __expf(l.x - mx.x) * inv.x;
        a.y = __expf(l.y - mx.y) * inv.y;
        a.z = __expf(l.z - mx.z) * inv.z;
        a.w = __expf(l.w - mx.w) * inv.w;
        int s = src[eid];
        const float* fr = ft + (size_t)s * 128;
        float f0 = fr[lane];
        float f1 = fr[lane + 64];
        float w0 = (lane < 32) ? a.x : a.y;  // j = lane      -> head 0 or 1
        float w1 = (lane < 32) ? a.z : a.w;  // j = lane + 64 -> head 2 or 3
        acc0 += w0 * f0;
        acc1 += w1 * f1;
    }
    op[lane] = fmaxf(acc0, 0.f);
    op[lane + 64] = fmaxf(acc1, 0.f);
}

// ---------------- launch ----------------

extern "C" void kernel_launch(void* const* d_in, const int* in_sizes, int n_in,
                              void* d_out, int out_size, void* d_ws, size_t ws_size,
                              hipStream_t stream) {
    const float* features = (const float*)d_in[0];
    const int* src = (const int*)d_in[1];
    const int* dst = (const int*)d_in[2];
    const float* w = (const float*)d_in[3];
    const float* W1 = (const float*)d_in[4];
    const float* al1 = (const float*)d_in[5];
    const float* ar1 = (const float*)d_in[6];
    const float* W2 = (const float*)d_in[7];
    const float* al2 = (const float*)d_in[8];
    const float* ar2 = (const float*)d_in[9];
    const float* Wout = (const float*)d_in[10];
    const float* bout = (const float*)d_in[11];
    float* out = (float*)d_out;

    int N = in_sizes[0] / 256;  // 50000
    int E = in_sizes[1];        // 400000

    char* ws = (char*)d_ws;
    size_t off = 0;
    auto alloc = [&](size_t bytes) -> void* {
        void* p = ws + off;
        off = (off + bytes + 255) & ~(size_t)255;
        return p;
    };
    int* cnt = (int*)alloc((size_t)N * 4);
    int* fill = (int*)alloc((size_t)N * 4);
    int* row_ptr = (int*)alloc((size_t)(N + 1) * 4);
    int* bsum = (int*)alloc(256 * 4);
    int* boff = (int*)alloc(256 * 4);
    int* csr = (int*)alloc((size_t)E * 4);
    float* ft = (float*)alloc((size_t)N * 128 * 4);
    float* el = (float*)alloc((size_t)N * 4 * 4);
    float* er = (float*)alloc((size_t)N * 4 * 4);
    float* logit = (float*)alloc((size_t)E * 4 * 4);
    float* h = (float*)alloc((size_t)N * 256 * 4);
    (void)ws_size; (void)n_in; (void)out_size;

    hipMemsetAsync(cnt, 0, (size_t)N * 4, stream);
    hipMemsetAsync(fill, 0, (size_t)N * 4, stream);

    int eb = (E + 255) / 256;   // 1563
    int nb = (N + 255) / 256;   // 196
    int wb = (N + 3) / 4;       // 12500 (4 waves/block, 1 node/wave)
    int gb = (N + 63) / 64;     // 782

    // CSR by dst
    hist_k<<<eb, 256, 0, stream>>>(dst, cnt, E);
    scan1_k<<<nb, 256, 0, stream>>>(cnt, row_ptr, bsum, N);
    scan2_k<<<1, 256, 0, stream>>>(bsum, boff, nb);
    scan3_k<<<nb, 256, 0, stream>>>(row_ptr, boff, N, E);
    scatter_k<<<eb, 256, 0, stream>>>(dst, row_ptr, fill, csr, E);

    // layer 1
    gemm_k<<<gb, 256, 0, stream>>>(features, 256, W1, nullptr, ft, N, 256);
    elr_k<<<wb, 256, 0, stream>>>(ft, al1, ar1, el, er, N);
    elog_k<<<eb, 256, 0, stream>>>((const float4*)el, (const float4*)er, src, dst, w,
                                   (float4*)logit, E);
    agg_k<<<wb, 256, 0, stream>>>(ft, (const float4*)logit, csr, row_ptr, src, h, 256, 0, N);

    // layer 2 (input = x1 = h[:, :128], lda 256)
    gemm_k<<<gb, 256, 0, stream>>>(h, 256, W2, nullptr, ft, N, 128);
    elr_k<<<wb, 256, 0, stream>>>(ft, al2, ar2, el, er, N);
    elog_k<<<eb, 256, 0, stream>>>((const float4*)el, (const float4*)er, src, dst, w,
                                   (float4*)logit, E);
    agg_k<<<wb, 256, 0, stream>>>(ft, (const float4*)logit, csr, row_ptr, src, h, 256, 128, N);

    // output: concat(x1,x2) = h [N,256]  ->  out = h @ Wout + bout
    gemm_k<<<gb, 256, 0, stream>>>(h, 256, Wout, bout, out, N, 256);
}

// Round 2
// 450.192 us; speedup vs baseline: 1.4133x; 1.4133x over previous
//
#include <hip/hip_runtime.h>
#include <math.h>

#define NHEAD 4
#define HDIM 32
#define NEG_SLOPE 0.1f

typedef unsigned short u16;
typedef unsigned int u32;
typedef __bf16 bf16x8 __attribute__((ext_vector_type(8)));
typedef float f32x4 __attribute__((ext_vector_type(4)));

// async 16B global->LDS (lds dest = wave-uniform base + lane*16)
#define GLLDS16(g, l) __builtin_amdgcn_global_load_lds( \
    (const __attribute__((address_space(1))) void*)(g), \
    (__attribute__((address_space(3))) void*)(l), 16, 0, 0)

__device__ __forceinline__ void split2(float v, u16& hi, u16& lo) {
    u32 u = __float_as_uint(v);
    hi = (u16)(u >> 16);
    float hif = __uint_as_float(u & 0xFFFF0000u);
    lo = (u16)(__float_as_uint(v - hif) >> 16);
}

// ---------------- CSR build ----------------

__global__ void hist_k(const int* __restrict__ dst, int* __restrict__ cnt, int E) {
    int e = blockIdx.x * 256 + threadIdx.x;
    if (e < E) atomicAdd(&cnt[dst[e]], 1);
}

__global__ void scan1_k(const int* __restrict__ cnt, int* __restrict__ row_ptr,
                        int* __restrict__ bsum, int N) {
    __shared__ int s[256];
    int t = threadIdx.x;
    int i = blockIdx.x * 256 + t;
    int v = (i < N) ? cnt[i] : 0;
    s[t] = v;
    __syncthreads();
    int incl = v;
    for (int off = 1; off < 256; off <<= 1) {
        int add = (t >= off) ? s[t - off] : 0;
        __syncthreads();
        incl += add;
        s[t] = incl;
        __syncthreads();
    }
    if (i < N) row_ptr[i] = incl - v;
    if (t == 255) bsum[blockIdx.x] = incl;
}

__global__ void scan2_k(const int* __restrict__ bsum, int* __restrict__ boff, int nb) {
    __shared__ int s[256];
    int t = threadIdx.x;
    int v = (t < nb) ? bsum[t] : 0;
    s[t] = v;
    __syncthreads();
    int incl = v;
    for (int off = 1; off < 256; off <<= 1) {
        int add = (t >= off) ? s[t - off] : 0;
        __syncthreads();
        incl += add;
        s[t] = incl;
        __syncthreads();
    }
    boff[t] = incl - v;
}

__global__ void scan3_k(int* __restrict__ row_ptr, const int* __restrict__ boff,
                        int N, int E) {
    int i = blockIdx.x * 256 + threadIdx.x;
    if (i < N) row_ptr[i] += boff[i >> 8];
    if (i == 0) row_ptr[N] = E;
}

__global__ void scatter_k(const int* __restrict__ dst, const int* __restrict__ row_ptr,
                          int* __restrict__ fill, int* __restrict__ csr, int E) {
    int e = blockIdx.x * 256 + threadIdx.x;
    if (e >= E) return;
    int d = dst[e];
    int p = atomicAdd(&fill[d], 1);
    csr[row_ptr[d] + p] = e;
}

// ---------------- casts ----------------

// features [M,256] fp32 -> hi/lo bf16 planes [Mpad,256]; pad rows zeroed
__global__ void castA_k(const float4* __restrict__ F, u16* __restrict__ fh,
                        u16* __restrict__ fl, int M, int Mpad) {
    int i = blockIdx.x * 256 + threadIdx.x;  // float4 index
    if (i >= Mpad * 64) return;
    int row = i >> 6;
    float4 v = make_float4(0.f, 0.f, 0.f, 0.f);
    if (row < M) v = F[i];
    u16 hx, lx, hy, ly, hz, lz, hw, lw;
    split2(v.x, hx, lx); split2(v.y, hy, ly);
    split2(v.z, hz, lz); split2(v.w, hw, lw);
    uint2 h2, l2;
    h2.x = (u32)hx | ((u32)hy << 16); h2.y = (u32)hz | ((u32)hw << 16);
    l2.x = (u32)lx | ((u32)ly << 16); l2.y = (u32)lz | ((u32)lw << 16);
    ((uint2*)fh)[i] = h2;
    ((uint2*)fl)[i] = l2;
}

// W [K,128] fp32 -> panel layout BP[kt][n][32kk] bf16 hi/lo (LDS-ready linear copy)
__global__ void castB_k(const float* __restrict__ W, u16* __restrict__ bh,
                        u16* __restrict__ bl, int K) {
    int t = blockIdx.x * 256 + threadIdx.x;  // pair index (2 consecutive kk)
    if (t >= K * 64) return;
    int kt = t >> 11;
    int rem = t & 2047;
    int n = rem >> 4;
    int kk = (rem & 15) * 2;
    int k = kt * 32 + kk;
    float w0 = W[(size_t)k * 128 + n];
    float w1 = W[(size_t)(k + 1) * 128 + n];
    u16 h0, l0, h1, l1;
    split2(w0, h0, l0);
    split2(w1, h1, l1);
    ((u32*)bh)[t] = (u32)h0 | ((u32)h1 << 16);
    ((u32*)bl)[t] = (u32)l0 | ((u32)l1 << 16);
}

// ---------------- split-bf16 MFMA GEMM: C[M,128] = (Ah+Al)[M,K](lda) @ B + bias ----------------
// block 256 (4 waves), tile 128x128, BK=32, 16x16x32 MFMA, hi*hi + hi*lo + lo*hi

__global__ __launch_bounds__(256) void gemm_sb_k(
        const u16* __restrict__ Ah, const u16* __restrict__ Al, int lda,
        const u16* __restrict__ Bh, const u16* __restrict__ Bl,
        const float* __restrict__ bias, float* __restrict__ C, int M, int K) {
    __shared__ u16 AsH[4096], AsL[4096], BsH[4096], BsL[4096];
    int tid = threadIdx.x;
    int w = tid >> 6, lane = tid & 63;
    int row0 = blockIdx.x * 128;
    int mrow = lane & 15;
    int koff = (lane >> 4) * 8;

    f32x4 acc[2][8];
#pragma unroll
    for (int mt = 0; mt < 2; mt++)
#pragma unroll
        for (int nt = 0; nt < 8; nt++) acc[mt][nt] = (f32x4){0.f, 0.f, 0.f, 0.f};

    for (int k0 = 0; k0 < K; k0 += 32) {
        int kt = k0 >> 5;
#pragma unroll
        for (int i = 0; i < 2; i++) {
            int call = w * 2 + i;
            int c = call * 64 + lane;          // chunk 0..511 (8 bf16 each)
            int r = c >> 2;
            int kk = (c & 3) << 3;
            size_t ga = (size_t)(row0 + r) * lda + (k0 + kk);
            GLLDS16(Ah + ga, &AsH[call * 512 + lane * 8]);
            GLLDS16(Al + ga, &AsL[call * 512 + lane * 8]);
            size_t gb = (size_t)kt * 4096 + (size_t)c * 8;
            GLLDS16(Bh + gb, &BsH[call * 512 + lane * 8]);
            GLLDS16(Bl + gb, &BsL[call * 512 + lane * 8]);
        }
        __syncthreads();  // drains vmcnt before barrier (compiler-inserted)

        bf16x8 ah[2], al[2];
#pragma unroll
        for (int mt = 0; mt < 2; mt++) {
            int off = (w * 32 + mt * 16 + mrow) * 32 + koff;
            ah[mt] = *(const bf16x8*)&AsH[off];
            al[mt] = *(const bf16x8*)&AsL[off];
        }
#pragma unroll
        for (int nt = 0; nt < 8; nt++) {
            int boff = (nt * 16 + mrow) * 32 + koff;
            bf16x8 bh = *(const bf16x8*)&BsH[boff];
            bf16x8 bl = *(const bf16x8*)&BsL[boff];
#pragma unroll
            for (int mt = 0; mt < 2; mt++) {
                acc[mt][nt] = __builtin_amdgcn_mfma_f32_16x16x32_bf16(ah[mt], bh, acc[mt][nt], 0, 0, 0);
                acc[mt][nt] = __builtin_amdgcn_mfma_f32_16x16x32_bf16(ah[mt], bl, acc[mt][nt], 0, 0, 0);
                acc[mt][nt] = __builtin_amdgcn_mfma_f32_16x16x32_bf16(al[mt], bh, acc[mt][nt], 0, 0, 0);
            }
        }
        __syncthreads();
    }

    // epilogue: C/D layout col=lane&15, row=(lane>>4)*4+reg
#pragma unroll
    for (int mt = 0; mt < 2; mt++) {
#pragma unroll
        for (int nt = 0; nt < 8; nt++) {
            int col = nt * 16 + mrow;
            int rbase = row0 + w * 32 + mt * 16 + (lane >> 4) * 4;
            float bv = bias ? bias[col] : 0.f;
            f32x4 v = acc[mt][nt];
#pragma unroll
            for (int reg = 0; reg < 4; reg++) {
                int rr = rbase + reg;
                if (rr < M) C[(size_t)rr * 128 + col] = v[reg] + bv;
            }
        }
    }
}

// ---------------- per-node attention logits ----------------

__global__ __launch_bounds__(256) void elr_k(const float* __restrict__ ft,
                                             const float* __restrict__ al,
                                             const float* __restrict__ ar,
                                             float* __restrict__ el, float* __restrict__ er,
                                             int N) {
    int n = blockIdx.x * 4 + (threadIdx.x >> 6);
    if (n >= N) return;
    int lane = threadIdx.x & 63;
    float f0 = ft[(size_t)n * 128 + lane];
    float f1 = ft[(size_t)n * 128 + 64 + lane];
    float e0 = f0 * al[lane], e1 = f1 * al[64 + lane];
    float r0 = f0 * ar[lane], r1 = f1 * ar[64 + lane];
    for (int m = 16; m >= 1; m >>= 1) {
        e0 += __shfl_xor(e0, m);
        e1 += __shfl_xor(e1, m);
        r0 += __shfl_xor(r0, m);
        r1 += __shfl_xor(r1, m);
    }
    if (lane == 0) {
        el[n * 4 + 0] = e0; el[n * 4 + 2] = e1;
        er[n * 4 + 0] = r0; er[n * 4 + 2] = r1;
    } else if (lane == 32) {
        el[n * 4 + 1] = e0; el[n * 4 + 3] = e1;
        er[n * 4 + 1] = r0; er[n * 4 + 3] = r1;
    }
}

// ---------------- per-edge logits ----------------

__global__ void elog_k(const float4* __restrict__ el4, const float4* __restrict__ er4,
                       const int* __restrict__ src, const int* __restrict__ dst,
                       const float* __restrict__ w, float4* __restrict__ logit, int E) {
    int e = blockIdx.x * 256 + threadIdx.x;
    if (e >= E) return;
    float4 a = el4[src[e]];
    float4 b = er4[dst[e]];
    float we = w[e];
    float4 l;
    l.x = a.x + b.x; l.x = we * (l.x > 0.f ? l.x : NEG_SLOPE * l.x);
    l.y = a.y + b.y; l.y = we * (l.y > 0.f ? l.y : NEG_SLOPE * l.y);
    l.z = a.z + b.z; l.z = we * (l.z > 0.f ? l.z : NEG_SLOPE * l.z);
    l.w = a.w + b.w; l.w = we * (l.w > 0.f ? l.w : NEG_SLOPE * l.w);
    logit[e] = l;
}

// ---------------- softmax + aggregation (writes bf16 hi/lo into concat buffer) ----------------

__global__ __launch_bounds__(256) void agg_k(const float* __restrict__ ft,
                                             const float4* __restrict__ logit,
                                             const int* __restrict__ csr,
                                             const int* __restrict__ row_ptr,
                                             const int* __restrict__ src,
                                             u16* __restrict__ hh, u16* __restrict__ hl,
                                             int ooff, int N) {
    int n = blockIdx.x * 4 + (threadIdx.x >> 6);
    if (n >= N) return;
    int lane = threadIdx.x & 63;
    int r0 = row_ptr[n], r1 = row_ptr[n + 1];
    int deg = r1 - r0;
    size_t ob = (size_t)n * 256 + ooff;
    if (deg == 0) {
        hh[ob + lane] = 0; hh[ob + lane + 64] = 0;
        hl[ob + lane] = 0; hl[ob + lane + 64] = 0;
        return;
    }
    float4 mx = make_float4(-INFINITY, -INFINITY, -INFINITY, -INFINITY);
    for (int i = lane; i < deg; i += 64) {
        float4 l = logit[csr[r0 + i]];
        mx.x = fmaxf(mx.x, l.x); mx.y = fmaxf(mx.y, l.y);
        mx.z = fmaxf(mx.z, l.z); mx.w = fmaxf(mx.w, l.w);
    }
    for (int m = 32; m >= 1; m >>= 1) {
        mx.x = fmaxf(mx.x, __shfl_xor(mx.x, m));
        mx.y = fmaxf(mx.y, __shfl_xor(mx.y, m));
        mx.z = fmaxf(mx.z, __shfl_xor(mx.z, m));
        mx.w = fmaxf(mx.w, __shfl_xor(mx.w, m));
    }
    float4 sm = make_float4(0.f, 0.f, 0.f, 0.f);
    for (int i = lane; i < deg; i += 64) {
        float4 l = logit[csr[r0 + i]];
        sm.x += __expf(l.x - mx.x); sm.y += __expf(l.y - mx.y);
        sm.z += __expf(l.z - mx.z); sm.w += __expf(l.w - mx.w);
    }
    for (int m = 32; m >= 1; m >>= 1) {
        sm.x += __shfl_xor(sm.x, m);
        sm.y += __shfl_xor(sm.y, m);
        sm.z += __shfl_xor(sm.z, m);
        sm.w += __shfl_xor(sm.w, m);
    }
    float4 inv;
    inv.x = 1.f / sm.x; inv.y = 1.f / sm.y; inv.z = 1.f / sm.z; inv.w = 1.f / sm.w;

    float acc0 = 0.f, acc1 = 0.f;
    for (int i = 0; i < deg; i++) {
        int eid = csr[r0 + i];
        float4 l = logit[eid];
        float4 a;
        a.x = __expf(l.x - mx.x) * inv.x;
        a.y = __expf(l.y - mx.y) * inv.y;
        a.z = __expf(l.z - mx.z) * inv.z;
        a.w = __expf(l.w - mx.w) * inv.w;
        int s = src[eid];
        const float* fr = ft + (size_t)s * 128;
        float f0 = fr[lane];
        float f1 = fr[lane + 64];
        float w0 = (lane < 32) ? a.x : a.y;
        float w1 = (lane < 32) ? a.z : a.w;
        acc0 += w0 * f0;
        acc1 += w1 * f1;
    }
    float v0 = fmaxf(acc0, 0.f);
    float v1 = fmaxf(acc1, 0.f);
    u16 h0, l0, h1, l1;
    split2(v0, h0, l0);
    split2(v1, h1, l1);
    hh[ob + lane] = h0; hl[ob + lane] = l0;
    hh[ob + lane + 64] = h1; hl[ob + lane + 64] = l1;
}

// ---------------- launch ----------------

extern "C" void kernel_launch(void* const* d_in, const int* in_sizes, int n_in,
                              void* d_out, int out_size, void* d_ws, size_t ws_size,
                              hipStream_t stream) {
    const float* features = (const float*)d_in[0];
    const int* src = (const int*)d_in[1];
    const int* dst = (const int*)d_in[2];
    const float* w = (const float*)d_in[3];
    const float* W1 = (const float*)d_in[4];
    const float* al1 = (const float*)d_in[5];
    const float* ar1 = (const float*)d_in[6];
    const float* W2 = (const float*)d_in[7];
    const float* al2 = (const float*)d_in[8];
    const float* ar2 = (const float*)d_in[9];
    const float* Wout = (const float*)d_in[10];
    const float* bout = (const float*)d_in[11];
    float* out = (float*)d_out;

    int N = in_sizes[0] / 256;           // 50000
    int E = in_sizes[1];                 // 400000
    int Mpad = ((N + 127) / 128) * 128;  // 50048

    char* ws = (char*)d_ws;
    size_t off = 0;
    auto alloc = [&](size_t bytes) -> void* {
        void* p = ws + off;
        off = (off + bytes + 255) & ~(size_t)255;
        return p;
    };
    int* cnt = (int*)alloc((size_t)N * 4);
    int* fill = (int*)alloc((size_t)N * 4);
    int* row_ptr = (int*)alloc((size_t)(N + 1) * 4);
    int* bsum = (int*)alloc(256 * 4);
    int* boff = (int*)alloc(256 * 4);
    int* csr = (int*)alloc((size_t)E * 4);
    float* ft = (float*)alloc((size_t)Mpad * 128 * 4);
    float* el = (float*)alloc((size_t)N * 4 * 4);
    float* er = (float*)alloc((size_t)N * 4 * 4);
    float* logit = (float*)alloc((size_t)E * 4 * 4);
    u16* xh_hi = (u16*)alloc((size_t)Mpad * 256 * 2);  // features-cast, then concat(x1,x2) hi
    u16* xh_lo = (u16*)alloc((size_t)Mpad * 256 * 2);  // lo plane (same aliasing)
    u16* bp_hi = (u16*)alloc((size_t)256 * 128 * 2);
    u16* bp_lo = (u16*)alloc((size_t)256 * 128 * 2);
    (void)ws_size; (void)n_in; (void)out_size;

    hipMemsetAsync(cnt, 0, (size_t)N * 4, stream);
    hipMemsetAsync(fill, 0, (size_t)N * 4, stream);

    int eb = (E + 255) / 256;
    int nb = (N + 255) / 256;
    int wb = (N + 3) / 4;
    int gb = Mpad / 128;                    // 391 blocks
    int cab = (Mpad * 64 + 255) / 256;      // castA blocks

    // CSR by dst
    hist_k<<<eb, 256, 0, stream>>>(dst, cnt, E);
    scan1_k<<<nb, 256, 0, stream>>>(cnt, row_ptr, bsum, N);
    scan2_k<<<1, 256, 0, stream>>>(bsum, boff, nb);
    scan3_k<<<nb, 256, 0, stream>>>(row_ptr, boff, N, E);
    scatter_k<<<eb, 256, 0, stream>>>(dst, row_ptr, fill, csr, E);

    // cast features -> bf16 hi/lo planes (pad rows zeroed)
    castA_k<<<cab, 256, 0, stream>>>((const float4*)features, xh_hi, xh_lo, N, Mpad);

    // layer 1: ft = features @ W1
    castB_k<<<(256 * 64 + 255) / 256, 256, 0, stream>>>(W1, bp_hi, bp_lo, 256);
    gemm_sb_k<<<gb, 256, 0, stream>>>(xh_hi, xh_lo, 256, bp_hi, bp_lo, nullptr, ft, N, 256);
    elr_k<<<wb, 256, 0, stream>>>(ft, al1, ar1, el, er, N);
    elog_k<<<eb, 256, 0, stream>>>((const float4*)el, (const float4*)er, src, dst, w,
                                   (float4*)logit, E);
    // agg1 overwrites xh cols 0..127 with x1 (features-cast fully consumed by gemm1)
    agg_k<<<wb, 256, 0, stream>>>(ft, (const float4*)logit, csr, row_ptr, src,
                                  xh_hi, xh_lo, 0, N);

    // layer 2: ft = x1 @ W2  (A = xh cols 0..127, lda 256)
    castB_k<<<(128 * 64 + 255) / 256, 256, 0, stream>>>(W2, bp_hi, bp_lo, 128);
    gemm_sb_k<<<gb, 256, 0, stream>>>(xh_hi, xh_lo, 256, bp_hi, bp_lo, nullptr, ft, N, 128);
    elr_k<<<wb, 256, 0, stream>>>(ft, al2, ar2, el, er, N);
    elog_k<<<eb, 256, 0, stream>>>((const float4*)el, (const float4*)er, src, dst, w,
                                   (float4*)logit, E);
    agg_k<<<wb, 256, 0, stream>>>(ft, (const float4*)logit, csr, row_ptr, src,
                                  xh_hi, xh_lo, 128, N);

    // output: out = concat(x1,x2) @ Wout + bout
    castB_k<<<(256 * 64 + 255) / 256, 256, 0, stream>>>(Wout, bp_hi, bp_lo, 256);
    gemm_sb_k<<<gb, 256, 0, stream>>>(xh_hi, xh_lo, 256, bp_hi, bp_lo, bout, out, N, 256);
}

// Round 3
// 389.300 us; speedup vs baseline: 1.6343x; 1.1564x over previous
//
#include <hip/hip_runtime.h>
#include <math.h>

#define NHEAD 4
#define HDIM 32
#define NEG_SLOPE 0.1f

typedef unsigned short u16;
typedef unsigned int u32;
typedef __bf16 bf16x8 __attribute__((ext_vector_type(8)));
typedef float f32x4 __attribute__((ext_vector_type(4)));

// async 16B global->LDS (lds dest = wave-uniform base + lane*16)
#define GLLDS16(g, l) __builtin_amdgcn_global_load_lds( \
    (const __attribute__((address_space(1))) void*)(g), \
    (__attribute__((address_space(3))) void*)(l), 16, 0, 0)

__device__ __forceinline__ void split2(float v, u16& hi, u16& lo) {
    u32 u = __float_as_uint(v);
    hi = (u16)(u >> 16);
    float hif = __uint_as_float(u & 0xFFFF0000u);
    lo = (u16)(__float_as_uint(v - hif) >> 16);
}

// ---------------- CSR build ----------------

__global__ void hist_k(const int* __restrict__ dst, int* __restrict__ cnt, int E) {
    int e = blockIdx.x * 256 + threadIdx.x;
    if (e < E) atomicAdd(&cnt[dst[e]], 1);
}

__global__ void scan1_k(const int* __restrict__ cnt, int* __restrict__ row_ptr,
                        int* __restrict__ bsum, int N) {
    __shared__ int s[256];
    int t = threadIdx.x;
    int i = blockIdx.x * 256 + t;
    int v = (i < N) ? cnt[i] : 0;
    s[t] = v;
    __syncthreads();
    int incl = v;
    for (int off = 1; off < 256; off <<= 1) {
        int add = (t >= off) ? s[t - off] : 0;
        __syncthreads();
        incl += add;
        s[t] = incl;
        __syncthreads();
    }
    if (i < N) row_ptr[i] = incl - v;
    if (t == 255) bsum[blockIdx.x] = incl;
}

__global__ void scan2_k(const int* __restrict__ bsum, int* __restrict__ boff, int nb) {
    __shared__ int s[256];
    int t = threadIdx.x;
    int v = (t < nb) ? bsum[t] : 0;
    s[t] = v;
    __syncthreads();
    int incl = v;
    for (int off = 1; off < 256; off <<= 1) {
        int add = (t >= off) ? s[t - off] : 0;
        __syncthreads();
        incl += add;
        s[t] = incl;
        __syncthreads();
    }
    boff[t] = incl - v;
}

__global__ void scan3_k(int* __restrict__ row_ptr, const int* __restrict__ boff,
                        int N, int E) {
    int i = blockIdx.x * 256 + threadIdx.x;
    if (i < N) row_ptr[i] += boff[i >> 8];
    if (i == 0) row_ptr[N] = E;
}

__global__ void scatter_k(const int* __restrict__ dst, const int* __restrict__ row_ptr,
                          int* __restrict__ fill, int* __restrict__ csr, int E) {
    int e = blockIdx.x * 256 + threadIdx.x;
    if (e >= E) return;
    int d = dst[e];
    int p = atomicAdd(&fill[d], 1);
    csr[row_ptr[d] + p] = e;
}

// ---------------- casts ----------------

__global__ void castA_k(const float4* __restrict__ F, u16* __restrict__ fh,
                        u16* __restrict__ fl, int M, int Mpad) {
    int i = blockIdx.x * 256 + threadIdx.x;  // float4 index
    if (i >= Mpad * 64) return;
    int row = i >> 6;
    float4 v = make_float4(0.f, 0.f, 0.f, 0.f);
    if (row < M) v = F[i];
    u16 hx, lx, hy, ly, hz, lz, hw, lw;
    split2(v.x, hx, lx); split2(v.y, hy, ly);
    split2(v.z, hz, lz); split2(v.w, hw, lw);
    uint2 h2, l2;
    h2.x = (u32)hx | ((u32)hy << 16); h2.y = (u32)hz | ((u32)hw << 16);
    l2.x = (u32)lx | ((u32)ly << 16); l2.y = (u32)lz | ((u32)lw << 16);
    ((uint2*)fh)[i] = h2;
    ((uint2*)fl)[i] = l2;
}

// W [K,128] fp32 -> panel layout BP[kt][n][32kk] bf16 hi/lo (LDS-ready linear copy)
__global__ void castB_k(const float* __restrict__ W, u16* __restrict__ bh,
                        u16* __restrict__ bl, int K) {
    int t = blockIdx.x * 256 + threadIdx.x;  // pair index (2 consecutive kk)
    if (t >= K * 64) return;
    int kt = t >> 11;
    int rem = t & 2047;
    int n = rem >> 4;
    int kk = (rem & 15) * 2;
    int k = kt * 32 + kk;
    float w0 = W[(size_t)k * 128 + n];
    float w1 = W[(size_t)(k + 1) * 128 + n];
    u16 h0, l0, h1, l1;
    split2(w0, h0, l0);
    split2(w1, h1, l1);
    ((u32*)bh)[t] = (u32)h0 | ((u32)h1 << 16);
    ((u32*)bl)[t] = (u32)l0 | ((u32)l1 << 16);
}

// ---------------- split-bf16 MFMA GEMM: C[M,128] = (Ah+Al)[M,K](lda) @ B + bias ----------------

__global__ __launch_bounds__(256) void gemm_sb_k(
        const u16* __restrict__ Ah, const u16* __restrict__ Al, int lda,
        const u16* __restrict__ Bh, const u16* __restrict__ Bl,
        const float* __restrict__ bias, float* __restrict__ C, int M, int K) {
    __shared__ u16 AsH[4096], AsL[4096], BsH[4096], BsL[4096];
    int tid = threadIdx.x;
    int w = tid >> 6, lane = tid & 63;
    int row0 = blockIdx.x * 128;
    int mrow = lane & 15;
    int koff = (lane >> 4) * 8;

    f32x4 acc[2][8];
#pragma unroll
    for (int mt = 0; mt < 2; mt++)
#pragma unroll
        for (int nt = 0; nt < 8; nt++) acc[mt][nt] = (f32x4){0.f, 0.f, 0.f, 0.f};

    for (int k0 = 0; k0 < K; k0 += 32) {
        int kt = k0 >> 5;
#pragma unroll
        for (int i = 0; i < 2; i++) {
            int call = w * 2 + i;
            int c = call * 64 + lane;          // chunk 0..511 (8 bf16 each)
            int r = c >> 2;
            int kk = (c & 3) << 3;
            size_t ga = (size_t)(row0 + r) * lda + (k0 + kk);
            GLLDS16(Ah + ga, &AsH[call * 512 + lane * 8]);
            GLLDS16(Al + ga, &AsL[call * 512 + lane * 8]);
            size_t gb = (size_t)kt * 4096 + (size_t)c * 8;
            GLLDS16(Bh + gb, &BsH[call * 512 + lane * 8]);
            GLLDS16(Bl + gb, &BsL[call * 512 + lane * 8]);
        }
        __syncthreads();

        bf16x8 ah[2], al[2];
#pragma unroll
        for (int mt = 0; mt < 2; mt++) {
            int off = (w * 32 + mt * 16 + mrow) * 32 + koff;
            ah[mt] = *(const bf16x8*)&AsH[off];
            al[mt] = *(const bf16x8*)&AsL[off];
        }
#pragma unroll
        for (int nt = 0; nt < 8; nt++) {
            int boff = (nt * 16 + mrow) * 32 + koff;
            bf16x8 bh = *(const bf16x8*)&BsH[boff];
            bf16x8 bl = *(const bf16x8*)&BsL[boff];
#pragma unroll
            for (int mt = 0; mt < 2; mt++) {
                acc[mt][nt] = __builtin_amdgcn_mfma_f32_16x16x32_bf16(ah[mt], bh, acc[mt][nt], 0, 0, 0);
                acc[mt][nt] = __builtin_amdgcn_mfma_f32_16x16x32_bf16(ah[mt], bl, acc[mt][nt], 0, 0, 0);
                acc[mt][nt] = __builtin_amdgcn_mfma_f32_16x16x32_bf16(al[mt], bh, acc[mt][nt], 0, 0, 0);
            }
        }
        __syncthreads();
    }

    // epilogue: C/D layout col=lane&15, row=(lane>>4)*4+reg
#pragma unroll
    for (int mt = 0; mt < 2; mt++) {
#pragma unroll
        for (int nt = 0; nt < 8; nt++) {
            int col = nt * 16 + mrow;
            int rbase = row0 + w * 32 + mt * 16 + (lane >> 4) * 4;
            float bv = bias ? bias[col] : 0.f;
            f32x4 v = acc[mt][nt];
#pragma unroll
            for (int reg = 0; reg < 4; reg++) {
                int rr = rbase + reg;
                if (rr < M) C[(size_t)rr * 128 + col] = v[reg] + bv;
            }
        }
    }
}

// ---------------- per-node attention logits ----------------

__global__ __launch_bounds__(256) void elr_k(const float* __restrict__ ft,
                                             const float* __restrict__ al,
                                             const float* __restrict__ ar,
                                             float* __restrict__ el, float* __restrict__ er,
                                             int N) {
    int n = blockIdx.x * 4 + (threadIdx.x >> 6);
    if (n >= N) return;
    int lane = threadIdx.x & 63;
    float f0 = ft[(size_t)n * 128 + lane];
    float f1 = ft[(size_t)n * 128 + 64 + lane];
    float e0 = f0 * al[lane], e1 = f1 * al[64 + lane];
    float r0 = f0 * ar[lane], r1 = f1 * ar[64 + lane];
    for (int m = 16; m >= 1; m >>= 1) {
        e0 += __shfl_xor(e0, m);
        e1 += __shfl_xor(e1, m);
        r0 += __shfl_xor(r0, m);
        r1 += __shfl_xor(r1, m);
    }
    if (lane == 0) {
        el[n * 4 + 0] = e0; el[n * 4 + 2] = e1;
        er[n * 4 + 0] = r0; er[n * 4 + 2] = r1;
    } else if (lane == 32) {
        el[n * 4 + 1] = e0; el[n * 4 + 3] = e1;
        er[n * 4 + 1] = r0; er[n * 4 + 3] = r1;
    }
}

// ---------------- per-edge logits ----------------

__global__ void elog_k(const float4* __restrict__ el4, const float4* __restrict__ er4,
                       const int* __restrict__ src, const int* __restrict__ dst,
                       const float* __restrict__ w, float4* __restrict__ logit, int E) {
    int e = blockIdx.x * 256 + threadIdx.x;
    if (e >= E) return;
    float4 a = el4[src[e]];
    float4 b = er4[dst[e]];
    float we = w[e];
    float4 l;
    l.x = a.x + b.x; l.x = we * (l.x > 0.f ? l.x : NEG_SLOPE * l.x);
    l.y = a.y + b.y; l.y = we * (l.y > 0.f ? l.y : NEG_SLOPE * l.y);
    l.z = a.z + b.z; l.z = we * (l.z > 0.f ? l.z : NEG_SLOPE * l.z);
    l.w = a.w + b.w; l.w = we * (l.w > 0.f ? l.w : NEG_SLOPE * l.w);
    logit[e] = l;
}

// ---------------- softmax + aggregation (lane-parallel softmax, shuffle-broadcast pass C) ----------------
// lane covers feature dims 2*lane, 2*lane+1; head = lane>>4. Writes bf16 hi/lo into concat buffer.

__global__ __launch_bounds__(256) void agg_k(const float* __restrict__ ft,
                                             const float4* __restrict__ logit,
                                             const int* __restrict__ csr,
                                             const int* __restrict__ row_ptr,
                                             const int* __restrict__ src,
                                             u16* __restrict__ hh, u16* __restrict__ hl,
                                             int ooff, int N) {
    int n = blockIdx.x * 4 + (threadIdx.x >> 6);
    if (n >= N) return;
    int lane = threadIdx.x & 63;
    int r0 = row_ptr[n], deg = row_ptr[n + 1] - r0;
    size_t ob = (size_t)n * 256 + ooff + 2 * lane;
    if (deg == 0) {
        *(u32*)&hh[ob] = 0;
        *(u32*)&hl[ob] = 0;
        return;
    }
    float acc0 = 0.f, acc1 = 0.f;
    if (deg <= 64) {
        // lane i owns edge i: one coalesced load of eid/logit/src each
        float4 l = make_float4(-INFINITY, -INFINITY, -INFINITY, -INFINITY);
        int s = 0;
        if (lane < deg) {
            int eid = csr[r0 + lane];
            l = logit[eid];
            s = src[eid];
        }
        float4 mx = l;
        for (int m = 32; m >= 1; m >>= 1) {
            mx.x = fmaxf(mx.x, __shfl_xor(mx.x, m));
            mx.y = fmaxf(mx.y, __shfl_xor(mx.y, m));
            mx.z = fmaxf(mx.z, __shfl_xor(mx.z, m));
            mx.w = fmaxf(mx.w, __shfl_xor(mx.w, m));
        }
        float4 a = make_float4(0.f, 0.f, 0.f, 0.f);
        if (lane < deg) {
            a.x = __expf(l.x - mx.x); a.y = __expf(l.y - mx.y);
            a.z = __expf(l.z - mx.z); a.w = __expf(l.w - mx.w);
        }
        float4 sm = a;
        for (int m = 32; m >= 1; m >>= 1) {
            sm.x += __shfl_xor(sm.x, m);
            sm.y += __shfl_xor(sm.y, m);
            sm.z += __shfl_xor(sm.z, m);
            sm.w += __shfl_xor(sm.w, m);
        }
        a.x = a.x / sm.x; a.y = a.y / sm.y;
        a.z = a.z / sm.z; a.w = a.w / sm.w;
        // pass C: shuffle-broadcast alpha+src from lane i; single float2 ft load per edge
        for (int i = 0; i < deg; i++) {
            int si = __shfl(s, i);
            float ax = __shfl(a.x, i), ay = __shfl(a.y, i);
            float az = __shfl(a.z, i), aw = __shfl(a.w, i);
            float wgt = lane < 16 ? ax : (lane < 32 ? ay : (lane < 48 ? az : aw));
            float2 f = ((const float2*)(ft + (size_t)si * 128))[lane];
            acc0 += wgt * f.x;
            acc1 += wgt * f.y;
        }
    } else {
        // fallback for deg > 64 (rare): lane-strided max/sum, wave-uniform serial aggregate
        float4 mx = make_float4(-INFINITY, -INFINITY, -INFINITY, -INFINITY);
        for (int i = lane; i < deg; i += 64) {
            float4 l = logit[csr[r0 + i]];
            mx.x = fmaxf(mx.x, l.x); mx.y = fmaxf(mx.y, l.y);
            mx.z = fmaxf(mx.z, l.z); mx.w = fmaxf(mx.w, l.w);
        }
        for (int m = 32; m >= 1; m >>= 1) {
            mx.x = fmaxf(mx.x, __shfl_xor(mx.x, m));
            mx.y = fmaxf(mx.y, __shfl_xor(mx.y, m));
            mx.z = fmaxf(mx.z, __shfl_xor(mx.z, m));
            mx.w = fmaxf(mx.w, __shfl_xor(mx.w, m));
        }
        float4 sm = make_float4(0.f, 0.f, 0.f, 0.f);
        for (int i = lane; i < deg; i += 64) {
            float4 l = logit[csr[r0 + i]];
            sm.x += __expf(l.x - mx.x); sm.y += __expf(l.y - mx.y);
            sm.z += __expf(l.z - mx.z); sm.w += __expf(l.w - mx.w);
        }
        for (int m = 32; m >= 1; m >>= 1) {
            sm.x += __shfl_xor(sm.x, m);
            sm.y += __shfl_xor(sm.y, m);
            sm.z += __shfl_xor(sm.z, m);
            sm.w += __shfl_xor(sm.w, m);
        }
        float4 inv;
        inv.x = 1.f / sm.x; inv.y = 1.f / sm.y;
        inv.z = 1.f / sm.z; inv.w = 1.f / sm.w;
        for (int i = 0; i < deg; i++) {
            int eid = csr[r0 + i];
            float4 l = logit[eid];
            float ax = __expf(l.x - mx.x) * inv.x;
            float ay = __expf(l.y - mx.y) * inv.y;
            float az = __expf(l.z - mx.z) * inv.z;
            float aw = __expf(l.w - mx.w) * inv.w;
            float wgt = lane < 16 ? ax : (lane < 32 ? ay : (lane < 48 ? az : aw));
            float2 f = ((const float2*)(ft + (size_t)src[eid] * 128))[lane];
            acc0 += wgt * f.x;
            acc1 += wgt * f.y;
        }
    }
    float v0 = fmaxf(acc0, 0.f);
    float v1 = fmaxf(acc1, 0.f);
    u16 h0, l0, h1, l1;
    split2(v0, h0, l0);
    split2(v1, h1, l1);
    *(u32*)&hh[ob] = (u32)h0 | ((u32)h1 << 16);
    *(u32*)&hl[ob] = (u32)l0 | ((u32)l1 << 16);
}

// ---------------- launch ----------------

extern "C" void kernel_launch(void* const* d_in, const int* in_sizes, int n_in,
                              void* d_out, int out_size, void* d_ws, size_t ws_size,
                              hipStream_t stream) {
    const float* features = (const float*)d_in[0];
    const int* src = (const int*)d_in[1];
    const int* dst = (const int*)d_in[2];
    const float* w = (const float*)d_in[3];
    const float* W1 = (const float*)d_in[4];
    const float* al1 = (const float*)d_in[5];
    const float* ar1 = (const float*)d_in[6];
    const float* W2 = (const float*)d_in[7];
    const float* al2 = (const float*)d_in[8];
    const float* ar2 = (const float*)d_in[9];
    const float* Wout = (const float*)d_in[10];
    const float* bout = (const float*)d_in[11];
    float* out = (float*)d_out;

    int N = in_sizes[0] / 256;           // 50000
    int E = in_sizes[1];                 // 400000
    int Mpad = ((N + 127) / 128) * 128;  // 50048

    char* ws = (char*)d_ws;
    size_t off = 0;
    auto alloc = [&](size_t bytes) -> void* {
        void* p = ws + off;
        off = (off + bytes + 255) & ~(size_t)255;
        return p;
    };
    int* cnt = (int*)alloc((size_t)N * 4);
    int* fill = (int*)alloc((size_t)N * 4);
    int* row_ptr = (int*)alloc((size_t)(N + 1) * 4);
    int* bsum = (int*)alloc(256 * 4);
    int* boff = (int*)alloc(256 * 4);
    int* csr = (int*)alloc((size_t)E * 4);
    float* ft = (float*)alloc((size_t)Mpad * 128 * 4);
    float* el = (float*)alloc((size_t)N * 4 * 4);
    float* er = (float*)alloc((size_t)N * 4 * 4);
    float* logit = (float*)alloc((size_t)E * 4 * 4);
    u16* xh_hi = (u16*)alloc((size_t)Mpad * 256 * 2);
    u16* xh_lo = (u16*)alloc((size_t)Mpad * 256 * 2);
    u16* bp_hi = (u16*)alloc((size_t)256 * 128 * 2);
    u16* bp_lo = (u16*)alloc((size_t)256 * 128 * 2);
    (void)ws_size; (void)n_in; (void)out_size;

    hipMemsetAsync(cnt, 0, (size_t)N * 4, stream);
    hipMemsetAsync(fill, 0, (size_t)N * 4, stream);

    int eb = (E + 255) / 256;
    int nb = (N + 255) / 256;
    int wb = (N + 3) / 4;
    int gb = Mpad / 128;
    int cab = (Mpad * 64 + 255) / 256;

    // CSR by dst
    hist_k<<<eb, 256, 0, stream>>>(dst, cnt, E);
    scan1_k<<<nb, 256, 0, stream>>>(cnt, row_ptr, bsum, N);
    scan2_k<<<1, 256, 0, stream>>>(bsum, boff, nb);
    scan3_k<<<nb, 256, 0, stream>>>(row_ptr, boff, N, E);
    scatter_k<<<eb, 256, 0, stream>>>(dst, row_ptr, fill, csr, E);

    // cast features -> bf16 hi/lo planes
    castA_k<<<cab, 256, 0, stream>>>((const float4*)features, xh_hi, xh_lo, N, Mpad);

    // layer 1
    castB_k<<<(256 * 64 + 255) / 256, 256, 0, stream>>>(W1, bp_hi, bp_lo, 256);
    gemm_sb_k<<<gb, 256, 0, stream>>>(xh_hi, xh_lo, 256, bp_hi, bp_lo, nullptr, ft, N, 256);
    elr_k<<<wb, 256, 0, stream>>>(ft, al1, ar1, el, er, N);
    elog_k<<<eb, 256, 0, stream>>>((const float4*)el, (const float4*)er, src, dst, w,
                                   (float4*)logit, E);
    agg_k<<<wb, 256, 0, stream>>>(ft, (const float4*)logit, csr, row_ptr, src,
                                  xh_hi, xh_lo, 0, N);

    // layer 2
    castB_k<<<(128 * 64 + 255) / 256, 256, 0, stream>>>(W2, bp_hi, bp_lo, 128);
    gemm_sb_k<<<gb, 256, 0, stream>>>(xh_hi, xh_lo, 256, bp_hi, bp_lo, nullptr, ft, N, 128);
    elr_k<<<wb, 256, 0, stream>>>(ft, al2, ar2, el, er, N);
    elog_k<<<eb, 256, 0, stream>>>((const float4*)el, (const float4*)er, src, dst, w,
                                   (float4*)logit, E);
    agg_k<<<wb, 256, 0, stream>>>(ft, (const float4*)logit, csr, row_ptr, src,
                                  xh_hi, xh_lo, 128, N);

    // output GEMM
    castB_k<<<(256 * 64 + 255) / 256, 256, 0, stream>>>(Wout, bp_hi, bp_lo, 256);
    gemm_sb_k<<<gb, 256, 0, stream>>>(xh_hi, xh_lo, 256, bp_hi, bp_lo, bout, out, N, 256);
}

// Round 4
// 351.376 us; speedup vs baseline: 1.8107x; 1.1079x over previous
//
#include <hip/hip_runtime.h>
#include <math.h>

#define NHEAD 4
#define HDIM 32
#define NEG_SLOPE 0.1f

typedef unsigned short u16;
typedef unsigned int u32;
typedef __bf16 bf16x8 __attribute__((ext_vector_type(8)));
typedef float f32x4 __attribute__((ext_vector_type(4)));

// async 16B global->LDS (lds dest = wave-uniform base + lane*16)
#define GLLDS16(g, l) __builtin_amdgcn_global_load_lds( \
    (const __attribute__((address_space(1))) void*)(g), \
    (__attribute__((address_space(3))) void*)(l), 16, 0, 0)

__device__ __forceinline__ void split2(float v, u16& hi, u16& lo) {
    u32 u = __float_as_uint(v);
    hi = (u16)(u >> 16);
    float hif = __uint_as_float(u & 0xFFFF0000u);
    lo = (u16)(__float_as_uint(v - hif) >> 16);
}

// round-to-nearest-even fp32 -> bf16
__device__ __forceinline__ u16 f2bf(float v) {
    u32 u = __float_as_uint(v);
    return (u16)((u + 0x7fff + ((u >> 16) & 1)) >> 16);
}

// ---------------- CSR build ----------------

__global__ void hist_k(const int* __restrict__ dst, int* __restrict__ cnt, int E) {
    int e = blockIdx.x * 256 + threadIdx.x;
    if (e < E) atomicAdd(&cnt[dst[e]], 1);
}

__global__ void scan1_k(const int* __restrict__ cnt, int* __restrict__ row_ptr,
                        int* __restrict__ bsum, int N) {
    __shared__ int s[256];
    int t = threadIdx.x;
    int i = blockIdx.x * 256 + t;
    int v = (i < N) ? cnt[i] : 0;
    s[t] = v;
    __syncthreads();
    int incl = v;
    for (int off = 1; off < 256; off <<= 1) {
        int add = (t >= off) ? s[t - off] : 0;
        __syncthreads();
        incl += add;
        s[t] = incl;
        __syncthreads();
    }
    if (i < N) row_ptr[i] = incl - v;
    if (t == 255) bsum[blockIdx.x] = incl;
}

__global__ void scan2_k(const int* __restrict__ bsum, int* __restrict__ boff, int nb) {
    __shared__ int s[256];
    int t = threadIdx.x;
    int v = (t < nb) ? bsum[t] : 0;
    s[t] = v;
    __syncthreads();
    int incl = v;
    for (int off = 1; off < 256; off <<= 1) {
        int add = (t >= off) ? s[t - off] : 0;
        __syncthreads();
        incl += add;
        s[t] = incl;
        __syncthreads();
    }
    boff[t] = incl - v;
}

__global__ void scan3_k(int* __restrict__ row_ptr, const int* __restrict__ boff,
                        int N, int E) {
    int i = blockIdx.x * 256 + threadIdx.x;
    if (i < N) row_ptr[i] += boff[i >> 8];
    if (i == 0) row_ptr[N] = E;
}

__global__ void scatter_k(const int* __restrict__ dst, const int* __restrict__ row_ptr,
                          int* __restrict__ fill, int* __restrict__ csr, int E) {
    int e = blockIdx.x * 256 + threadIdx.x;
    if (e >= E) return;
    int d = dst[e];
    int p = atomicAdd(&fill[d], 1);
    csr[row_ptr[d] + p] = e;
}

// ---------------- casts ----------------

__global__ void castA_k(const float4* __restrict__ F, u16* __restrict__ fh,
                        u16* __restrict__ fl, int M, int Mpad) {
    int i = blockIdx.x * 256 + threadIdx.x;  // float4 index
    if (i >= Mpad * 64) return;
    int row = i >> 6;
    float4 v = make_float4(0.f, 0.f, 0.f, 0.f);
    if (row < M) v = F[i];
    u16 hx, lx, hy, ly, hz, lz, hw, lw;
    split2(v.x, hx, lx); split2(v.y, hy, ly);
    split2(v.z, hz, lz); split2(v.w, hw, lw);
    uint2 h2, l2;
    h2.x = (u32)hx | ((u32)hy << 16); h2.y = (u32)hz | ((u32)hw << 16);
    l2.x = (u32)lx | ((u32)ly << 16); l2.y = (u32)lz | ((u32)lw << 16);
    ((uint2*)fh)[i] = h2;
    ((uint2*)fl)[i] = l2;
}

// W [K,128] fp32 -> panel layout BP[kt][n][32kk] bf16 hi/lo (LDS-ready linear copy)
__global__ void castB_k(const float* __restrict__ W, u16* __restrict__ bh,
                        u16* __restrict__ bl, int K) {
    int t = blockIdx.x * 256 + threadIdx.x;  // pair index (2 consecutive kk)
    if (t >= K * 64) return;
    int kt = t >> 11;
    int rem = t & 2047;
    int n = rem >> 4;
    int kk = (rem & 15) * 2;
    int k = kt * 32 + kk;
    float w0 = W[(size_t)k * 128 + n];
    float w1 = W[(size_t)(k + 1) * 128 + n];
    u16 h0, l0, h1, l1;
    split2(w0, h0, l0);
    split2(w1, h1, l1);
    ((u32*)bh)[t] = (u32)h0 | ((u32)h1 << 16);
    ((u32*)bl)[t] = (u32)l0 | ((u32)l1 << 16);
}

// ---------------- split-bf16 MFMA GEMM: C = (Ah+Al)[M,K](lda) @ B + bias ----------------
// Cf (fp32, nullable) and/or Cb (bf16, nullable) outputs.

__global__ __launch_bounds__(256) void gemm_sb_k(
        const u16* __restrict__ Ah, const u16* __restrict__ Al, int lda,
        const u16* __restrict__ Bh, const u16* __restrict__ Bl,
        const float* __restrict__ bias, float* __restrict__ Cf,
        u16* __restrict__ Cb, int M, int K) {
    __shared__ u16 AsH[4096], AsL[4096], BsH[4096], BsL[4096];
    int tid = threadIdx.x;
    int w = tid >> 6, lane = tid & 63;
    int row0 = blockIdx.x * 128;
    int mrow = lane & 15;
    int koff = (lane >> 4) * 8;

    f32x4 acc[2][8];
#pragma unroll
    for (int mt = 0; mt < 2; mt++)
#pragma unroll
        for (int nt = 0; nt < 8; nt++) acc[mt][nt] = (f32x4){0.f, 0.f, 0.f, 0.f};

    for (int k0 = 0; k0 < K; k0 += 32) {
        int kt = k0 >> 5;
#pragma unroll
        for (int i = 0; i < 2; i++) {
            int call = w * 2 + i;
            int c = call * 64 + lane;          // chunk 0..511 (8 bf16 each)
            int r = c >> 2;
            int kk = (c & 3) << 3;
            size_t ga = (size_t)(row0 + r) * lda + (k0 + kk);
            GLLDS16(Ah + ga, &AsH[call * 512 + lane * 8]);
            GLLDS16(Al + ga, &AsL[call * 512 + lane * 8]);
            size_t gb = (size_t)kt * 4096 + (size_t)c * 8;
            GLLDS16(Bh + gb, &BsH[call * 512 + lane * 8]);
            GLLDS16(Bl + gb, &BsL[call * 512 + lane * 8]);
        }
        __syncthreads();

        bf16x8 ah[2], al[2];
#pragma unroll
        for (int mt = 0; mt < 2; mt++) {
            int off = (w * 32 + mt * 16 + mrow) * 32 + koff;
            ah[mt] = *(const bf16x8*)&AsH[off];
            al[mt] = *(const bf16x8*)&AsL[off];
        }
#pragma unroll
        for (int nt = 0; nt < 8; nt++) {
            int boff = (nt * 16 + mrow) * 32 + koff;
            bf16x8 bh = *(const bf16x8*)&BsH[boff];
            bf16x8 bl = *(const bf16x8*)&BsL[boff];
#pragma unroll
            for (int mt = 0; mt < 2; mt++) {
                acc[mt][nt] = __builtin_amdgcn_mfma_f32_16x16x32_bf16(ah[mt], bh, acc[mt][nt], 0, 0, 0);
                acc[mt][nt] = __builtin_amdgcn_mfma_f32_16x16x32_bf16(ah[mt], bl, acc[mt][nt], 0, 0, 0);
                acc[mt][nt] = __builtin_amdgcn_mfma_f32_16x16x32_bf16(al[mt], bh, acc[mt][nt], 0, 0, 0);
            }
        }
        __syncthreads();
    }

    // epilogue: C/D layout col=lane&15, row=(lane>>4)*4+reg
#pragma unroll
    for (int mt = 0; mt < 2; mt++) {
#pragma unroll
        for (int nt = 0; nt < 8; nt++) {
            int col = nt * 16 + mrow;
            int rbase = row0 + w * 32 + mt * 16 + (lane >> 4) * 4;
            float bv = bias ? bias[col] : 0.f;
            f32x4 v = acc[mt][nt];
#pragma unroll
            for (int reg = 0; reg < 4; reg++) {
                int rr = rbase + reg;
                if (rr < M) {
                    float val = v[reg] + bv;
                    if (Cf) Cf[(size_t)rr * 128 + col] = val;
                    if (Cb) Cb[(size_t)rr * 128 + col] = f2bf(val);
                }
            }
        }
    }
}

// ---------------- per-node attention logits from bf16 ft ----------------
// lane covers dims 2*lane, 2*lane+1; head = lane>>4; reduce within 16-lane group.

__global__ __launch_bounds__(256) void elrb_k(const u32* __restrict__ ftb2,
                                              const float* __restrict__ al,
                                              const float* __restrict__ ar,
                                              float* __restrict__ el, float* __restrict__ er,
                                              int N) {
    int n = blockIdx.x * 4 + (threadIdx.x >> 6);
    if (n >= N) return;
    int lane = threadIdx.x & 63;
    u32 p = ftb2[(size_t)n * 64 + lane];
    float f0 = __uint_as_float(p << 16);
    float f1 = __uint_as_float(p & 0xFFFF0000u);
    float e = f0 * al[2 * lane] + f1 * al[2 * lane + 1];
    float r = f0 * ar[2 * lane] + f1 * ar[2 * lane + 1];
    for (int m = 8; m >= 1; m >>= 1) {
        e += __shfl_xor(e, m);
        r += __shfl_xor(r, m);
    }
    if ((lane & 15) == 0) {
        el[n * 4 + (lane >> 4)] = e;
        er[n * 4 + (lane >> 4)] = r;
    }
}

// ---------------- per-edge logits ----------------

__global__ void elog_k(const float4* __restrict__ el4, const float4* __restrict__ er4,
                       const int* __restrict__ src, const int* __restrict__ dst,
                       const float* __restrict__ w, float4* __restrict__ logit, int E) {
    int e = blockIdx.x * 256 + threadIdx.x;
    if (e >= E) return;
    float4 a = el4[src[e]];
    float4 b = er4[dst[e]];
    float we = w[e];
    float4 l;
    l.x = a.x + b.x; l.x = we * (l.x > 0.f ? l.x : NEG_SLOPE * l.x);
    l.y = a.y + b.y; l.y = we * (l.y > 0.f ? l.y : NEG_SLOPE * l.y);
    l.z = a.z + b.z; l.z = we * (l.z > 0.f ? l.z : NEG_SLOPE * l.z);
    l.w = a.w + b.w; l.w = we * (l.w > 0.f ? l.w : NEG_SLOPE * l.w);
    logit[e] = l;
}

// ---------------- softmax + aggregation (bf16 gather, LDS-staged alpha/src) ----------------
// lane covers feature dims 2*lane, 2*lane+1; head = lane>>4.

__global__ __launch_bounds__(256) void agg_k(const u32* __restrict__ ftb2,
                                             const float4* __restrict__ logit,
                                             const int* __restrict__ csr,
                                             const int* __restrict__ row_ptr,
                                             const int* __restrict__ src,
                                             u16* __restrict__ hh, u16* __restrict__ hl,
                                             int ooff, int N) {
    __shared__ float4 sA[256];  // [wave*64 + edge] normalized alphas
    __shared__ int sS[256];     // [wave*64 + edge] src node
    int wv = threadIdx.x >> 6;
    int n = blockIdx.x * 4 + wv;
    if (n >= N) return;
    int lane = threadIdx.x & 63;
    int head = lane >> 4;
    int r0 = row_ptr[n], deg = row_ptr[n + 1] - r0;
    size_t ob = (size_t)n * 256 + ooff + 2 * lane;
    if (deg == 0) {
        *(u32*)&hh[ob] = 0;
        *(u32*)&hl[ob] = 0;
        return;
    }
    float acc0 = 0.f, acc1 = 0.f;
    if (deg <= 64) {
        // lane i owns edge i
        float4 l = make_float4(-INFINITY, -INFINITY, -INFINITY, -INFINITY);
        int s = 0;
        if (lane < deg) {
            int eid = csr[r0 + lane];
            l = logit[eid];
            s = src[eid];
        }
        float4 mx = l;
        for (int m = 32; m >= 1; m >>= 1) {
            mx.x = fmaxf(mx.x, __shfl_xor(mx.x, m));
            mx.y = fmaxf(mx.y, __shfl_xor(mx.y, m));
            mx.z = fmaxf(mx.z, __shfl_xor(mx.z, m));
            mx.w = fmaxf(mx.w, __shfl_xor(mx.w, m));
        }
        float4 a = make_float4(0.f, 0.f, 0.f, 0.f);
        if (lane < deg) {
            a.x = __expf(l.x - mx.x); a.y = __expf(l.y - mx.y);
            a.z = __expf(l.z - mx.z); a.w = __expf(l.w - mx.w);
        }
        float4 sm = a;
        for (int m = 32; m >= 1; m >>= 1) {
            sm.x += __shfl_xor(sm.x, m);
            sm.y += __shfl_xor(sm.y, m);
            sm.z += __shfl_xor(sm.z, m);
            sm.w += __shfl_xor(sm.w, m);
        }
        a.x = a.x / sm.x; a.y = a.y / sm.y;
        a.z = a.z / sm.z; a.w = a.w / sm.w;
        // stage alpha/src in LDS (per-wave private; DS ops in-order within wave)
        sA[wv * 64 + lane] = a;
        sS[wv * 64 + lane] = s;
        const float* sAf = (const float*)&sA[wv * 64];
        const int* sSp = &sS[wv * 64];
        for (int i = 0; i < deg; i++) {
            float wgt = sAf[i * 4 + head];      // 4 distinct addrs -> 4 banks, broadcast in-group
            int si = sSp[i];                    // wave-uniform -> broadcast
            u32 p = ftb2[(size_t)si * 64 + lane];
            acc0 += wgt * __uint_as_float(p << 16);
            acc1 += wgt * __uint_as_float(p & 0xFFFF0000u);
        }
    } else {
        // fallback for deg > 64 (rare)
        float4 mx = make_float4(-INFINITY, -INFINITY, -INFINITY, -INFINITY);
        for (int i = lane; i < deg; i += 64) {
            float4 l = logit[csr[r0 + i]];
            mx.x = fmaxf(mx.x, l.x); mx.y = fmaxf(mx.y, l.y);
            mx.z = fmaxf(mx.z, l.z); mx.w = fmaxf(mx.w, l.w);
        }
        for (int m = 32; m >= 1; m >>= 1) {
            mx.x = fmaxf(mx.x, __shfl_xor(mx.x, m));
            mx.y = fmaxf(mx.y, __shfl_xor(mx.y, m));
            mx.z = fmaxf(mx.z, __shfl_xor(mx.z, m));
            mx.w = fmaxf(mx.w, __shfl_xor(mx.w, m));
        }
        float4 sm = make_float4(0.f, 0.f, 0.f, 0.f);
        for (int i = lane; i < deg; i += 64) {
            float4 l = logit[csr[r0 + i]];
            sm.x += __expf(l.x - mx.x); sm.y += __expf(l.y - mx.y);
            sm.z += __expf(l.z - mx.z); sm.w += __expf(l.w - mx.w);
        }
        for (int m = 32; m >= 1; m >>= 1) {
            sm.x += __shfl_xor(sm.x, m);
            sm.y += __shfl_xor(sm.y, m);
            sm.z += __shfl_xor(sm.z, m);
            sm.w += __shfl_xor(sm.w, m);
        }
        float4 inv;
        inv.x = 1.f / sm.x; inv.y = 1.f / sm.y;
        inv.z = 1.f / sm.z; inv.w = 1.f / sm.w;
        for (int i = 0; i < deg; i++) {
            int eid = csr[r0 + i];
            float4 l = logit[eid];
            float ax = __expf(l.x - mx.x) * inv.x;
            float ay = __expf(l.y - mx.y) * inv.y;
            float az = __expf(l.z - mx.z) * inv.z;
            float aw = __expf(l.w - mx.w) * inv.w;
            float wgt = head == 0 ? ax : (head == 1 ? ay : (head == 2 ? az : aw));
            u32 p = ftb2[(size_t)src[eid] * 64 + lane];
            acc0 += wgt * __uint_as_float(p << 16);
            acc1 += wgt * __uint_as_float(p & 0xFFFF0000u);
        }
    }
    float v0 = fmaxf(acc0, 0.f);
    float v1 = fmaxf(acc1, 0.f);
    u16 h0, l0, h1, l1;
    split2(v0, h0, l0);
    split2(v1, h1, l1);
    *(u32*)&hh[ob] = (u32)h0 | ((u32)h1 << 16);
    *(u32*)&hl[ob] = (u32)l0 | ((u32)l1 << 16);
}

// ---------------- launch ----------------

extern "C" void kernel_launch(void* const* d_in, const int* in_sizes, int n_in,
                              void* d_out, int out_size, void* d_ws, size_t ws_size,
                              hipStream_t stream) {
    const float* features = (const float*)d_in[0];
    const int* src = (const int*)d_in[1];
    const int* dst = (const int*)d_in[2];
    const float* w = (const float*)d_in[3];
    const float* W1 = (const float*)d_in[4];
    const float* al1 = (const float*)d_in[5];
    const float* ar1 = (const float*)d_in[6];
    const float* W2 = (const float*)d_in[7];
    const float* al2 = (const float*)d_in[8];
    const float* ar2 = (const float*)d_in[9];
    const float* Wout = (const float*)d_in[10];
    const float* bout = (const float*)d_in[11];
    float* out = (float*)d_out;

    int N = in_sizes[0] / 256;           // 50000
    int E = in_sizes[1];                 // 400000
    int Mpad = ((N + 127) / 128) * 128;  // 50048

    char* ws = (char*)d_ws;
    size_t off = 0;
    auto alloc = [&](size_t bytes) -> void* {
        void* p = ws + off;
        off = (off + bytes + 255) & ~(size_t)255;
        return p;
    };
    int* cnt = (int*)alloc((size_t)N * 4);
    int* fill = (int*)alloc((size_t)N * 4);
    int* row_ptr = (int*)alloc((size_t)(N + 1) * 4);
    int* bsum = (int*)alloc(256 * 4);
    int* boff = (int*)alloc(256 * 4);
    int* csr = (int*)alloc((size_t)E * 4);
    u16* ftb = (u16*)alloc((size_t)Mpad * 128 * 2);  // bf16 node features (per layer)
    float* el = (float*)alloc((size_t)N * 4 * 4);
    float* er = (float*)alloc((size_t)N * 4 * 4);
    float* logit = (float*)alloc((size_t)E * 4 * 4);
    u16* xh_hi = (u16*)alloc((size_t)Mpad * 256 * 2);
    u16* xh_lo = (u16*)alloc((size_t)Mpad * 256 * 2);
    u16* bp_hi = (u16*)alloc((size_t)256 * 128 * 2);
    u16* bp_lo = (u16*)alloc((size_t)256 * 128 * 2);
    (void)ws_size; (void)n_in; (void)out_size;

    hipMemsetAsync(cnt, 0, (size_t)N * 4, stream);
    hipMemsetAsync(fill, 0, (size_t)N * 4, stream);

    int eb = (E + 255) / 256;
    int nb = (N + 255) / 256;
    int wb = (N + 3) / 4;
    int gb = Mpad / 128;
    int cab = (Mpad * 64 + 255) / 256;

    // CSR by dst
    hist_k<<<eb, 256, 0, stream>>>(dst, cnt, E);
    scan1_k<<<nb, 256, 0, stream>>>(cnt, row_ptr, bsum, N);
    scan2_k<<<1, 256, 0, stream>>>(bsum, boff, nb);
    scan3_k<<<nb, 256, 0, stream>>>(row_ptr, boff, N, E);
    scatter_k<<<eb, 256, 0, stream>>>(dst, row_ptr, fill, csr, E);

    // cast features -> bf16 hi/lo planes
    castA_k<<<cab, 256, 0, stream>>>((const float4*)features, xh_hi, xh_lo, N, Mpad);

    // layer 1: ftb = bf16(features @ W1)
    castB_k<<<(256 * 64 + 255) / 256, 256, 0, stream>>>(W1, bp_hi, bp_lo, 256);
    gemm_sb_k<<<gb, 256, 0, stream>>>(xh_hi, xh_lo, 256, bp_hi, bp_lo, nullptr,
                                      nullptr, ftb, N, 256);
    elrb_k<<<wb, 256, 0, stream>>>((const u32*)ftb, al1, ar1, el, er, N);
    elog_k<<<eb, 256, 0, stream>>>((const float4*)el, (const float4*)er, src, dst, w,
                                   (float4*)logit, E);
    agg_k<<<wb, 256, 0, stream>>>((const u32*)ftb, (const float4*)logit, csr, row_ptr, src,
                                  xh_hi, xh_lo, 0, N);

    // layer 2: ftb = bf16(x1 @ W2)
    castB_k<<<(128 * 64 + 255) / 256, 256, 0, stream>>>(W2, bp_hi, bp_lo, 128);
    gemm_sb_k<<<gb, 256, 0, stream>>>(xh_hi, xh_lo, 256, bp_hi, bp_lo, nullptr,
                                      nullptr, ftb, N, 128);
    elrb_k<<<wb, 256, 0, stream>>>((const u32*)ftb, al2, ar2, el, er, N);
    elog_k<<<eb, 256, 0, stream>>>((const float4*)el, (const float4*)er, src, dst, w,
                                   (float4*)logit, E);
    agg_k<<<wb, 256, 0, stream>>>((const u32*)ftb, (const float4*)logit, csr, row_ptr, src,
                                  xh_hi, xh_lo, 128, N);

    // output GEMM (fp32 out)
    castB_k<<<(256 * 64 + 255) / 256, 256, 0, stream>>>(Wout, bp_hi, bp_lo, 256);
    gemm_sb_k<<<gb, 256, 0, stream>>>(xh_hi, xh_lo, 256, bp_hi, bp_lo, bout,
                                      out, nullptr, N, 256);
}

// Round 5
// 316.970 us; speedup vs baseline: 2.0073x; 1.1085x over previous
//
#include <hip/hip_runtime.h>
#include <math.h>

#define NHEAD 4
#define HDIM 32
#define NEG_SLOPE 0.1f

typedef unsigned short u16;
typedef unsigned int u32;
typedef __bf16 bf16x8 __attribute__((ext_vector_type(8)));
typedef float f32x4 __attribute__((ext_vector_type(4)));

// async 16B global->LDS (lds dest = wave-uniform base + lane*16)
#define GLLDS16(g, l) __builtin_amdgcn_global_load_lds( \
    (const __attribute__((address_space(1))) void*)(g), \
    (__attribute__((address_space(3))) void*)(l), 16, 0, 0)

__device__ __forceinline__ void split2(float v, u16& hi, u16& lo) {
    u32 u = __float_as_uint(v);
    hi = (u16)(u >> 16);
    float hif = __uint_as_float(u & 0xFFFF0000u);
    lo = (u16)(__float_as_uint(v - hif) >> 16);
}

// round-to-nearest-even fp32 -> bf16
__device__ __forceinline__ u16 f2bf(float v) {
    u32 u = __float_as_uint(v);
    return (u16)((u + 0x7fff + ((u >> 16) & 1)) >> 16);
}

// ---------------- CSR build ----------------

__global__ void hist_k(const int* __restrict__ dst, int* __restrict__ cnt, int E) {
    int e = blockIdx.x * 256 + threadIdx.x;
    if (e < E) atomicAdd(&cnt[dst[e]], 1);
}

__global__ void scan1_k(const int* __restrict__ cnt, int* __restrict__ row_ptr,
                        int* __restrict__ bsum, int N) {
    __shared__ int s[256];
    int t = threadIdx.x;
    int i = blockIdx.x * 256 + t;
    int v = (i < N) ? cnt[i] : 0;
    s[t] = v;
    __syncthreads();
    int incl = v;
    for (int off = 1; off < 256; off <<= 1) {
        int add = (t >= off) ? s[t - off] : 0;
        __syncthreads();
        incl += add;
        s[t] = incl;
        __syncthreads();
    }
    if (i < N) row_ptr[i] = incl - v;
    if (t == 255) bsum[blockIdx.x] = incl;
}

__global__ void scan2_k(const int* __restrict__ bsum, int* __restrict__ boff, int nb) {
    __shared__ int s[256];
    int t = threadIdx.x;
    int v = (t < nb) ? bsum[t] : 0;
    s[t] = v;
    __syncthreads();
    int incl = v;
    for (int off = 1; off < 256; off <<= 1) {
        int add = (t >= off) ? s[t - off] : 0;
        __syncthreads();
        incl += add;
        s[t] = incl;
        __syncthreads();
    }
    boff[t] = incl - v;
}

__global__ void scan3_k(int* __restrict__ row_ptr, const int* __restrict__ boff,
                        int N, int E) {
    int i = blockIdx.x * 256 + threadIdx.x;
    if (i < N) row_ptr[i] += boff[i >> 8];
    if (i == 0) row_ptr[N] = E;
}

// scatter edges into CSR order, carrying src and w (no eid indirection later)
__global__ void scatter_k(const int* __restrict__ src, const int* __restrict__ dst,
                          const float* __restrict__ w, const int* __restrict__ row_ptr,
                          int* __restrict__ fill, int* __restrict__ src_s,
                          float* __restrict__ w_s, int E) {
    int e = blockIdx.x * 256 + threadIdx.x;
    if (e >= E) return;
    int d = dst[e];
    int p = atomicAdd(&fill[d], 1);
    int idx = row_ptr[d] + p;
    src_s[idx] = src[e];
    w_s[idx] = w[e];
}

// ---------------- weight cast: all three W -> bf16 hi/lo panels in one dispatch ----------------
// panel layout BP[kt][n][32kk], pair-packed (2 consecutive kk per u32)

__device__ __forceinline__ void castB_one(const float* W, u16* bh, u16* bl, int t) {
    int kt = t >> 11;
    int rem = t & 2047;
    int n = rem >> 4;
    int kk = (rem & 15) * 2;
    int k = kt * 32 + kk;
    float w0 = W[(size_t)k * 128 + n];
    float w1 = W[(size_t)(k + 1) * 128 + n];
    u16 h0, l0, h1, l1;
    split2(w0, h0, l0);
    split2(w1, h1, l1);
    ((u32*)bh)[t] = (u32)h0 | ((u32)h1 << 16);
    ((u32*)bl)[t] = (u32)l0 | ((u32)l1 << 16);
}

__global__ void castB3_k(const float* __restrict__ W1, u16* __restrict__ b1h, u16* __restrict__ b1l,
                         const float* __restrict__ W2, u16* __restrict__ b2h, u16* __restrict__ b2l,
                         const float* __restrict__ W3, u16* __restrict__ b3h, u16* __restrict__ b3l) {
    int t = blockIdx.x * 256 + threadIdx.x;
    if (t < 16384) castB_one(W1, b1h, b1l, t);               // K=256
    else if (t < 24576) castB_one(W2, b2h, b2l, t - 16384);  // K=128
    else if (t < 40960) castB_one(W3, b3h, b3l, t - 24576);  // K=256
}

// ---------------- split-bf16 MFMA GEMM, fp32 A: C = A[M,K](lda) @ B + bias ----------------
// A is fp32, split to bf16 hi/lo during LDS staging. Tile 128x128, BK=32.
// Cf (fp32, nullable) and/or Cb (bf16, nullable) outputs.

__global__ __launch_bounds__(256) void gemm_fa_k(
        const float* __restrict__ A, int lda,
        const u16* __restrict__ Bh, const u16* __restrict__ Bl,
        const float* __restrict__ bias, float* __restrict__ Cf,
        u16* __restrict__ Cb, int M, int K) {
    __shared__ u16 AsH[4096], AsL[4096], BsH[4096], BsL[4096];
    int tid = threadIdx.x;
    int w = tid >> 6, lane = tid & 63;
    int row0 = blockIdx.x * 128;
    int mrow = lane & 15;
    int koff = (lane >> 4) * 8;

    f32x4 acc[2][8];
#pragma unroll
    for (int mt = 0; mt < 2; mt++)
#pragma unroll
        for (int nt = 0; nt < 8; nt++) acc[mt][nt] = (f32x4){0.f, 0.f, 0.f, 0.f};

    for (int k0 = 0; k0 < K; k0 += 32) {
        int kt = k0 >> 5;
        // B: async global->LDS (panel is LDS-ready linear)
#pragma unroll
        for (int i = 0; i < 2; i++) {
            int c = (w * 2 + i) * 64 + lane;   // chunk 0..511 (8 u16 each)
            size_t gb = (size_t)kt * 4096 + (size_t)c * 8;
            GLLDS16(Bh + gb, &BsH[c * 8]);
            GLLDS16(Bl + gb, &BsL[c * 8]);
        }
        // A: fp32 load -> split -> LDS (128 rows x 32 k; 1024 float4, 4/thread)
#pragma unroll
        for (int i = 0; i < 4; i++) {
            int flat = tid + i * 256;          // 0..1023
            int r = flat >> 3, c4 = flat & 7;
            int row = min(row0 + r, M - 1);    // clamp: pad-row results discarded in epilogue
            float4 v = *(const float4*)&A[(size_t)row * lda + k0 + c4 * 4];
            u16 h0, l0, h1, l1, h2, l2, h3, l3;
            split2(v.x, h0, l0); split2(v.y, h1, l1);
            split2(v.z, h2, l2); split2(v.w, h3, l3);
            uint2 hp, lp;
            hp.x = (u32)h0 | ((u32)h1 << 16); hp.y = (u32)h2 | ((u32)h3 << 16);
            lp.x = (u32)l0 | ((u32)l1 << 16); lp.y = (u32)l2 | ((u32)l3 << 16);
            *(uint2*)&AsH[r * 32 + c4 * 4] = hp;
            *(uint2*)&AsL[r * 32 + c4 * 4] = lp;
        }
        __syncthreads();

        bf16x8 ah[2], al[2];
#pragma unroll
        for (int mt = 0; mt < 2; mt++) {
            int off = (w * 32 + mt * 16 + mrow) * 32 + koff;
            ah[mt] = *(const bf16x8*)&AsH[off];
            al[mt] = *(const bf16x8*)&AsL[off];
        }
#pragma unroll
        for (int nt = 0; nt < 8; nt++) {
            int boff = (nt * 16 + mrow) * 32 + koff;
            bf16x8 bh = *(const bf16x8*)&BsH[boff];
            bf16x8 bl = *(const bf16x8*)&BsL[boff];
#pragma unroll
            for (int mt = 0; mt < 2; mt++) {
                acc[mt][nt] = __builtin_amdgcn_mfma_f32_16x16x32_bf16(ah[mt], bh, acc[mt][nt], 0, 0, 0);
                acc[mt][nt] = __builtin_amdgcn_mfma_f32_16x16x32_bf16(ah[mt], bl, acc[mt][nt], 0, 0, 0);
                acc[mt][nt] = __builtin_amdgcn_mfma_f32_16x16x32_bf16(al[mt], bh, acc[mt][nt], 0, 0, 0);
            }
        }
        __syncthreads();
    }

    // epilogue: C/D layout col=lane&15, row=(lane>>4)*4+reg
#pragma unroll
    for (int mt = 0; mt < 2; mt++) {
#pragma unroll
        for (int nt = 0; nt < 8; nt++) {
            int col = nt * 16 + mrow;
            int rbase = row0 + w * 32 + mt * 16 + (lane >> 4) * 4;
            float bv = bias ? bias[col] : 0.f;
            f32x4 v = acc[mt][nt];
#pragma unroll
            for (int reg = 0; reg < 4; reg++) {
                int rr = rbase + reg;
                if (rr < M) {
                    float val = v[reg] + bv;
                    if (Cf) Cf[(size_t)rr * 128 + col] = val;
                    if (Cb) Cb[(size_t)rr * 128 + col] = f2bf(val);
                }
            }
        }
    }
}

// ---------------- per-node attention logits from bf16 ft ----------------
// lane covers dims 2*lane, 2*lane+1; head = lane>>4; reduce within 16-lane group.

__global__ __launch_bounds__(256) void elrb_k(const u32* __restrict__ ftb2,
                                              const float* __restrict__ al,
                                              const float* __restrict__ ar,
                                              float* __restrict__ el, float* __restrict__ er,
                                              int N) {
    int n = blockIdx.x * 4 + (threadIdx.x >> 6);
    if (n >= N) return;
    int lane = threadIdx.x & 63;
    u32 p = ftb2[(size_t)n * 64 + lane];
    float f0 = __uint_as_float(p << 16);
    float f1 = __uint_as_float(p & 0xFFFF0000u);
    float e = f0 * al[2 * lane] + f1 * al[2 * lane + 1];
    float r = f0 * ar[2 * lane] + f1 * ar[2 * lane + 1];
    for (int m = 8; m >= 1; m >>= 1) {
        e += __shfl_xor(e, m);
        r += __shfl_xor(r, m);
    }
    if ((lane & 15) == 0) {
        el[n * 4 + (lane >> 4)] = e;
        er[n * 4 + (lane >> 4)] = r;
    }
}

// ---------------- fused logits + softmax + aggregation ----------------
// lane covers feature dims 2*lane, 2*lane+1; head = lane>>4. Writes fp32 into concat buffer.

__device__ __forceinline__ float lrelu(float x) {
    return x > 0.f ? x : NEG_SLOPE * x;
}

__global__ __launch_bounds__(256) void agg_k(const u32* __restrict__ ftb2,
                                             const float4* __restrict__ el4,
                                             const float4* __restrict__ er4,
                                             const int* __restrict__ src_s,
                                             const float* __restrict__ w_s,
                                             const int* __restrict__ row_ptr,
                                             float* __restrict__ xcat,
                                             int ooff, int N) {
    __shared__ float4 sA[256];  // [wave*64 + edge] normalized alphas
    __shared__ int sS[256];     // [wave*64 + edge] src node
    int wv = threadIdx.x >> 6;
    int n = blockIdx.x * 4 + wv;
    if (n >= N) return;
    int lane = threadIdx.x & 63;
    int head = lane >> 4;
    int r0 = row_ptr[n], deg = row_ptr[n + 1] - r0;
    float* op = &xcat[(size_t)n * 256 + ooff + 2 * lane];
    if (deg == 0) {
        *(float2*)op = make_float2(0.f, 0.f);
        return;
    }
    float4 ern = er4[n];  // wave-uniform
    float acc0 = 0.f, acc1 = 0.f;
    if (deg <= 64) {
        // lane i owns edge i: coalesced src/w, gathered el
        float4 l = make_float4(-INFINITY, -INFINITY, -INFINITY, -INFINITY);
        int s = 0;
        if (lane < deg) {
            s = src_s[r0 + lane];
            float we = w_s[r0 + lane];
            float4 e = el4[s];
            l.x = we * lrelu(e.x + ern.x);
            l.y = we * lrelu(e.y + ern.y);
            l.z = we * lrelu(e.z + ern.z);
            l.w = we * lrelu(e.w + ern.w);
        }
        float4 mx = l;
        for (int m = 32; m >= 1; m >>= 1) {
            mx.x = fmaxf(mx.x, __shfl_xor(mx.x, m));
            mx.y = fmaxf(mx.y, __shfl_xor(mx.y, m));
            mx.z = fmaxf(mx.z, __shfl_xor(mx.z, m));
            mx.w = fmaxf(mx.w, __shfl_xor(mx.w, m));
        }
        float4 a = make_float4(0.f, 0.f, 0.f, 0.f);
        if (lane < deg) {
            a.x = __expf(l.x - mx.x); a.y = __expf(l.y - mx.y);
            a.z = __expf(l.z - mx.z); a.w = __expf(l.w - mx.w);
        }
        float4 sm = a;
        for (int m = 32; m >= 1; m >>= 1) {
            sm.x += __shfl_xor(sm.x, m);
            sm.y += __shfl_xor(sm.y, m);
            sm.z += __shfl_xor(sm.z, m);
            sm.w += __shfl_xor(sm.w, m);
        }
        a.x = a.x / sm.x; a.y = a.y / sm.y;
        a.z = a.z / sm.z; a.w = a.w / sm.w;
        // stage alpha/src in LDS (per-wave private; DS ops in-order within wave)
        sA[wv * 64 + lane] = a;
        sS[wv * 64 + lane] = s;
        const float* sAf = (const float*)&sA[wv * 64];
        const int* sSp = &sS[wv * 64];
        int i = 0;
        for (; i + 4 <= deg; i += 4) {  // 4 independent gathers in flight
            float w0 = sAf[(i + 0) * 4 + head];
            float w1 = sAf[(i + 1) * 4 + head];
            float w2 = sAf[(i + 2) * 4 + head];
            float w3 = sAf[(i + 3) * 4 + head];
            int s0 = sSp[i + 0], s1 = sSp[i + 1], s2 = sSp[i + 2], s3 = sSp[i + 3];
            u32 p0 = ftb2[(size_t)s0 * 64 + lane];
            u32 p1 = ftb2[(size_t)s1 * 64 + lane];
            u32 p2 = ftb2[(size_t)s2 * 64 + lane];
            u32 p3 = ftb2[(size_t)s3 * 64 + lane];
            acc0 += w0 * __uint_as_float(p0 << 16);
            acc1 += w0 * __uint_as_float(p0 & 0xFFFF0000u);
            acc0 += w1 * __uint_as_float(p1 << 16);
            acc1 += w1 * __uint_as_float(p1 & 0xFFFF0000u);
            acc0 += w2 * __uint_as_float(p2 << 16);
            acc1 += w2 * __uint_as_float(p2 & 0xFFFF0000u);
            acc0 += w3 * __uint_as_float(p3 << 16);
            acc1 += w3 * __uint_as_float(p3 & 0xFFFF0000u);
        }
        for (; i < deg; i++) {
            float wgt = sAf[i * 4 + head];
            int si = sSp[i];
            u32 p = ftb2[(size_t)si * 64 + lane];
            acc0 += wgt * __uint_as_float(p << 16);
            acc1 += wgt * __uint_as_float(p & 0xFFFF0000u);
        }
    } else {
        // fallback for deg > 64 (rare): recompute logits per pass
        float4 mx = make_float4(-INFINITY, -INFINITY, -INFINITY, -INFINITY);
        for (int i = lane; i < deg; i += 64) {
            float we = w_s[r0 + i];
            float4 e = el4[src_s[r0 + i]];
            mx.x = fmaxf(mx.x, we * lrelu(e.x + ern.x));
            mx.y = fmaxf(mx.y, we * lrelu(e.y + ern.y));
            mx.z = fmaxf(mx.z, we * lrelu(e.z + ern.z));
            mx.w = fmaxf(mx.w, we * lrelu(e.w + ern.w));
        }
        for (int m = 32; m >= 1; m >>= 1) {
            mx.x = fmaxf(mx.x, __shfl_xor(mx.x, m));
            mx.y = fmaxf(mx.y, __shfl_xor(mx.y, m));
            mx.z = fmaxf(mx.z, __shfl_xor(mx.z, m));
            mx.w = fmaxf(mx.w, __shfl_xor(mx.w, m));
        }
        float4 sm = make_float4(0.f, 0.f, 0.f, 0.f);
        for (int i = lane; i < deg; i += 64) {
            float we = w_s[r0 + i];
            float4 e = el4[src_s[r0 + i]];
            sm.x += __expf(we * lrelu(e.x + ern.x) - mx.x);
            sm.y += __expf(we * lrelu(e.y + ern.y) - mx.y);
            sm.z += __expf(we * lrelu(e.z + ern.z) - mx.z);
            sm.w += __expf(we * lrelu(e.w + ern.w) - mx.w);
        }
        for (int m = 32; m >= 1; m >>= 1) {
            sm.x += __shfl_xor(sm.x, m);
            sm.y += __shfl_xor(sm.y, m);
            sm.z += __shfl_xor(sm.z, m);
            sm.w += __shfl_xor(sm.w, m);
        }
        float4 inv;
        inv.x = 1.f / sm.x; inv.y = 1.f / sm.y;
        inv.z = 1.f / sm.z; inv.w = 1.f / sm.w;
        for (int i = 0; i < deg; i++) {
            int si = src_s[r0 + i];
            float we = w_s[r0 + i];
            float4 e = el4[si];
            float ax = __expf(we * lrelu(e.x + ern.x) - mx.x) * inv.x;
            float ay = __expf(we * lrelu(e.y + ern.y) - mx.y) * inv.y;
            float az = __expf(we * lrelu(e.z + ern.z) - mx.z) * inv.z;
            float aw = __expf(we * lrelu(e.w + ern.w) - mx.w) * inv.w;
            float wgt = head == 0 ? ax : (head == 1 ? ay : (head == 2 ? az : aw));
            u32 p = ftb2[(size_t)si * 64 + lane];
            acc0 += wgt * __uint_as_float(p << 16);
            acc1 += wgt * __uint_as_float(p & 0xFFFF0000u);
        }
    }
    *(float2*)op = make_float2(fmaxf(acc0, 0.f), fmaxf(acc1, 0.f));
}

// ---------------- launch ----------------

extern "C" void kernel_launch(void* const* d_in, const int* in_sizes, int n_in,
                              void* d_out, int out_size, void* d_ws, size_t ws_size,
                              hipStream_t stream) {
    const float* features = (const float*)d_in[0];
    const int* src = (const int*)d_in[1];
    const int* dst = (const int*)d_in[2];
    const float* w = (const float*)d_in[3];
    const float* W1 = (const float*)d_in[4];
    const float* al1 = (const float*)d_in[5];
    const float* ar1 = (const float*)d_in[6];
    const float* W2 = (const float*)d_in[7];
    const float* al2 = (const float*)d_in[8];
    const float* ar2 = (const float*)d_in[9];
    const float* Wout = (const float*)d_in[10];
    const float* bout = (const float*)d_in[11];
    float* out = (float*)d_out;

    int N = in_sizes[0] / 256;           // 50000
    int E = in_sizes[1];                 // 400000
    int Mpad = ((N + 127) / 128) * 128;  // 50048

    char* ws = (char*)d_ws;
    size_t off = 0;
    auto alloc = [&](size_t bytes) -> void* {
        void* p = ws + off;
        off = (off + bytes + 255) & ~(size_t)255;
        return p;
    };
    size_t Nr = ((size_t)N * 4 + 255) & ~(size_t)255;
    int* cnt = (int*)alloc(2 * Nr);                  // cnt + fill contiguous (single memset)
    int* fill = (int*)((char*)cnt + Nr);
    int* row_ptr = (int*)alloc((size_t)(N + 1) * 4);
    int* bsum = (int*)alloc(256 * 4);
    int* boff = (int*)alloc(256 * 4);
    int* src_s = (int*)alloc((size_t)E * 4);
    float* w_s = (float*)alloc((size_t)E * 4);
    u16* ftb = (u16*)alloc((size_t)Mpad * 128 * 2);  // bf16 node features (per layer)
    float* el = (float*)alloc((size_t)N * 4 * 4);
    float* er = (float*)alloc((size_t)N * 4 * 4);
    float* xcat = (float*)alloc((size_t)Mpad * 256 * 4);  // concat(x1,x2) fp32
    u16* b1h = (u16*)alloc((size_t)256 * 128 * 2);
    u16* b1l = (u16*)alloc((size_t)256 * 128 * 2);
    u16* b2h = (u16*)alloc((size_t)128 * 128 * 2);
    u16* b2l = (u16*)alloc((size_t)128 * 128 * 2);
    u16* b3h = (u16*)alloc((size_t)256 * 128 * 2);
    u16* b3l = (u16*)alloc((size_t)256 * 128 * 2);
    (void)ws_size; (void)n_in; (void)out_size;

    hipMemsetAsync(cnt, 0, 2 * Nr, stream);

    int eb = (E + 255) / 256;
    int nb = (N + 255) / 256;
    int wb = (N + 3) / 4;
    int gb = Mpad / 128;

    // CSR by dst (carrying src/w)
    hist_k<<<eb, 256, 0, stream>>>(dst, cnt, E);
    scan1_k<<<nb, 256, 0, stream>>>(cnt, row_ptr, bsum, N);
    scan2_k<<<1, 256, 0, stream>>>(bsum, boff, nb);
    scan3_k<<<nb, 256, 0, stream>>>(row_ptr, boff, N, E);
    scatter_k<<<eb, 256, 0, stream>>>(src, dst, w, row_ptr, fill, src_s, w_s, E);

    // all three weight panels in one dispatch
    castB3_k<<<160, 256, 0, stream>>>(W1, b1h, b1l, W2, b2h, b2l, Wout, b3h, b3l);

    // layer 1: ftb = bf16(features @ W1)
    gemm_fa_k<<<gb, 256, 0, stream>>>(features, 256, b1h, b1l, nullptr,
                                      nullptr, ftb, N, 256);
    elrb_k<<<wb, 256, 0, stream>>>((const u32*)ftb, al1, ar1, el, er, N);
    agg_k<<<wb, 256, 0, stream>>>((const u32*)ftb, (const float4*)el, (const float4*)er,
                                  src_s, w_s, row_ptr, xcat, 0, N);

    // layer 2: ftb = bf16(x1 @ W2)   (A = xcat cols 0..127, lda 256)
    gemm_fa_k<<<gb, 256, 0, stream>>>(xcat, 256, b2h, b2l, nullptr,
                                      nullptr, ftb, N, 128);
    elrb_k<<<wb, 256, 0, stream>>>((const u32*)ftb, al2, ar2, el, er, N);
    agg_k<<<wb, 256, 0, stream>>>((const u32*)ftb, (const float4*)el, (const float4*)er,
                                  src_s, w_s, row_ptr, xcat, 128, N);

    // output GEMM: out = xcat @ Wout + bout
    gemm_fa_k<<<gb, 256, 0, stream>>>(xcat, 256, b3h, b3l, bout,
                                      out, nullptr, N, 256);
}

// Round 6
// 306.471 us; speedup vs baseline: 2.0760x; 1.0343x over previous
//
#include <hip/hip_runtime.h>
#include <math.h>

#define NHEAD 4
#define HDIM 32
#define NEG_SLOPE 0.1f

typedef unsigned short u16;
typedef unsigned int u32;
typedef _Float16 f16;
typedef f16 f16x2 __attribute__((ext_vector_type(2)));
typedef f16 f16x4 __attribute__((ext_vector_type(4)));
typedef f16 f16x8 __attribute__((ext_vector_type(8)));
typedef float f32x4 __attribute__((ext_vector_type(4)));

// async 16B global->LDS (lds dest = wave-uniform base + lane*16)
#define GLLDS16(g, l) __builtin_amdgcn_global_load_lds( \
    (const __attribute__((address_space(1))) void*)(g), \
    (__attribute__((address_space(3))) void*)(l), 16, 0, 0)

// ---------------- CSR build ----------------

__global__ void hist_k(const int* __restrict__ dst, int* __restrict__ cnt, int E) {
    int e = blockIdx.x * 256 + threadIdx.x;
    if (e < E) atomicAdd(&cnt[dst[e]], 1);
}

__global__ void scan1_k(const int* __restrict__ cnt, int* __restrict__ row_ptr,
                        int* __restrict__ bsum, int N) {
    __shared__ int s[256];
    int t = threadIdx.x;
    int i = blockIdx.x * 256 + t;
    int v = (i < N) ? cnt[i] : 0;
    s[t] = v;
    __syncthreads();
    int incl = v;
    for (int off = 1; off < 256; off <<= 1) {
        int add = (t >= off) ? s[t - off] : 0;
        __syncthreads();
        incl += add;
        s[t] = incl;
        __syncthreads();
    }
    if (i < N) row_ptr[i] = incl - v;
    if (t == 255) bsum[blockIdx.x] = incl;
}

__global__ void scan2_k(const int* __restrict__ bsum, int* __restrict__ boff, int nb) {
    __shared__ int s[256];
    int t = threadIdx.x;
    int v = (t < nb) ? bsum[t] : 0;
    s[t] = v;
    __syncthreads();
    int incl = v;
    for (int off = 1; off < 256; off <<= 1) {
        int add = (t >= off) ? s[t - off] : 0;
        __syncthreads();
        incl += add;
        s[t] = incl;
        __syncthreads();
    }
    boff[t] = incl - v;
}

__global__ void scan3_k(int* __restrict__ row_ptr, const int* __restrict__ boff,
                        int N, int E) {
    int i = blockIdx.x * 256 + threadIdx.x;
    if (i < N) row_ptr[i] += boff[i >> 8];
    if (i == 0) row_ptr[N] = E;
}

// scatter edges into CSR order, carrying src and w
__global__ void scatter_k(const int* __restrict__ src, const int* __restrict__ dst,
                          const float* __restrict__ w, const int* __restrict__ row_ptr,
                          int* __restrict__ fill, int* __restrict__ src_s,
                          float* __restrict__ w_s, int E) {
    int e = blockIdx.x * 256 + threadIdx.x;
    if (e >= E) return;
    int d = dst[e];
    int p = atomicAdd(&fill[d], 1);
    int idx = row_ptr[d] + p;
    src_s[idx] = src[e];
    w_s[idx] = w[e];
}

// ---------------- weight cast: all three W -> fp16 panels in one dispatch ----------------
// panel layout BP[kt][n][32kk], pair-packed (2 consecutive kk per u32)

__device__ __forceinline__ void castB_one(const float* W, u16* bp, int t) {
    int kt = t >> 11;
    int rem = t & 2047;
    int n = rem >> 4;
    int kk = (rem & 15) * 2;
    int k = kt * 32 + kk;
    f16x2 p;
    p.x = (f16)W[(size_t)k * 128 + n];
    p.y = (f16)W[(size_t)(k + 1) * 128 + n];
    *(f16x2*)&((u32*)bp)[t] = p;
}

__global__ void castB3_k(const float* __restrict__ W1, u16* __restrict__ b1,
                         const float* __restrict__ W2, u16* __restrict__ b2,
                         const float* __restrict__ W3, u16* __restrict__ b3) {
    int t = blockIdx.x * 256 + threadIdx.x;
    if (t < 16384) castB_one(W1, b1, t);               // K=256
    else if (t < 24576) castB_one(W2, b2, t - 16384);  // K=128
    else if (t < 40960) castB_one(W3, b3, t - 24576);  // K=256
}

// ---------------- fp16 MFMA GEMM: C = A[M,K](lda) @ B + bias ----------------
// A either fp32 (cvt during staging) or fp16 (async global->LDS).
// Tile 128x128, BK=32, 16x16x32 f16 MFMA. Cf (fp32) or Ch (fp16) outputs.

__global__ __launch_bounds__(256) void gemm_h_k(
        const void* __restrict__ Av, int a_is_f16, int lda,
        const u16* __restrict__ Bp,
        const float* __restrict__ bias, float* __restrict__ Cf,
        u16* __restrict__ Ch, int M, int K) {
    __shared__ u16 As[4096], Bs[4096];
    int tid = threadIdx.x;
    int w = tid >> 6, lane = tid & 63;
    int row0 = blockIdx.x * 128;
    int mrow = lane & 15;
    int koff = (lane >> 4) * 8;

    f32x4 acc[2][8];
#pragma unroll
    for (int mt = 0; mt < 2; mt++)
#pragma unroll
        for (int nt = 0; nt < 8; nt++) acc[mt][nt] = (f32x4){0.f, 0.f, 0.f, 0.f};

    for (int k0 = 0; k0 < K; k0 += 32) {
        int kt = k0 >> 5;
        // B: async global->LDS (panel is LDS-ready linear), 512 chunks of 16B
#pragma unroll
        for (int i = 0; i < 2; i++) {
            int c = (w * 2 + i) * 64 + lane;
            GLLDS16(Bp + (size_t)kt * 4096 + (size_t)c * 8, &Bs[c * 8]);
        }
        if (a_is_f16) {
            // A fp16: async global->LDS, 512 chunks (row r=c>>2, kchunk c&3)
            const u16* Ah = (const u16*)Av;
#pragma unroll
            for (int i = 0; i < 2; i++) {
                int c = (w * 2 + i) * 64 + lane;
                int r = c >> 2, kk = (c & 3) << 3;
                GLLDS16(Ah + (size_t)(row0 + r) * lda + k0 + kk, &As[c * 8]);
            }
        } else {
            // A fp32: load float4, cvt to fp16, store LDS (1024 float4, 4/thread)
            const float* Af = (const float*)Av;
#pragma unroll
            for (int i = 0; i < 4; i++) {
                int flat = tid + i * 256;
                int r = flat >> 3, c4 = flat & 7;
                int row = min(row0 + r, M - 1);  // clamp; pad rows discarded in epilogue
                float4 v = *(const float4*)&Af[(size_t)row * lda + k0 + c4 * 4];
                f16x4 p;
                p.x = (f16)v.x; p.y = (f16)v.y; p.z = (f16)v.z; p.w = (f16)v.w;
                *(f16x4*)&As[r * 32 + c4 * 4] = p;
            }
        }
        __syncthreads();

        f16x8 ah[2];
#pragma unroll
        for (int mt = 0; mt < 2; mt++)
            ah[mt] = *(const f16x8*)&As[(w * 32 + mt * 16 + mrow) * 32 + koff];
#pragma unroll
        for (int nt = 0; nt < 8; nt++) {
            f16x8 bh = *(const f16x8*)&Bs[(nt * 16 + mrow) * 32 + koff];
#pragma unroll
            for (int mt = 0; mt < 2; mt++)
                acc[mt][nt] = __builtin_amdgcn_mfma_f32_16x16x32_f16(ah[mt], bh, acc[mt][nt], 0, 0, 0);
        }
        __syncthreads();
    }

    // epilogue: C/D layout col=lane&15, row=(lane>>4)*4+reg
#pragma unroll
    for (int mt = 0; mt < 2; mt++) {
#pragma unroll
        for (int nt = 0; nt < 8; nt++) {
            int col = nt * 16 + mrow;
            int rbase = row0 + w * 32 + mt * 16 + (lane >> 4) * 4;
            float bv = bias ? bias[col] : 0.f;
            f32x4 v = acc[mt][nt];
#pragma unroll
            for (int reg = 0; reg < 4; reg++) {
                int rr = rbase + reg;
                if (rr < M) {
                    float val = v[reg] + bv;
                    if (Cf) Cf[(size_t)rr * 128 + col] = val;
                    if (Ch) *(f16*)&Ch[(size_t)rr * 128 + col] = (f16)val;
                }
            }
        }
    }
}

// ---------------- per-node attention logits from fp16 ft ----------------
// lane covers dims 2*lane, 2*lane+1; head = lane>>4; reduce within 16-lane group.

__global__ __launch_bounds__(256) void elrh_k(const u32* __restrict__ fth2,
                                              const float* __restrict__ al,
                                              const float* __restrict__ ar,
                                              float* __restrict__ el, float* __restrict__ er,
                                              int N) {
    int n = blockIdx.x * 4 + (threadIdx.x >> 6);
    if (n >= N) return;
    int lane = threadIdx.x & 63;
    u32 p = fth2[(size_t)n * 64 + lane];
    f16x2 hp = *(const f16x2*)&p;
    float f0 = (float)hp.x, f1 = (float)hp.y;
    float e = f0 * al[2 * lane] + f1 * al[2 * lane + 1];
    float r = f0 * ar[2 * lane] + f1 * ar[2 * lane + 1];
    for (int m = 8; m >= 1; m >>= 1) {
        e += __shfl_xor(e, m);
        r += __shfl_xor(r, m);
    }
    if ((lane & 15) == 0) {
        el[n * 4 + (lane >> 4)] = e;
        er[n * 4 + (lane >> 4)] = r;
    }
}

// ---------------- fused logits + softmax + aggregation ----------------
// lane covers feature dims 2*lane, 2*lane+1; head = lane>>4. Writes fp16 into concat buffer.

__device__ __forceinline__ float lrelu(float x) {
    return x > 0.f ? x : NEG_SLOPE * x;
}

__global__ __launch_bounds__(256) void agg_k(const u32* __restrict__ fth2,
                                             const float4* __restrict__ el4,
                                             const float4* __restrict__ er4,
                                             const int* __restrict__ src_s,
                                             const float* __restrict__ w_s,
                                             const int* __restrict__ row_ptr,
                                             u16* __restrict__ xcat,
                                             int ooff, int N) {
    __shared__ float4 sA[256];  // [wave*64 + edge] normalized alphas
    __shared__ int sS[256];     // [wave*64 + edge] src node
    int wv = threadIdx.x >> 6;
    int n = blockIdx.x * 4 + wv;
    if (n >= N) return;
    int lane = threadIdx.x & 63;
    int head = lane >> 4;
    int r0 = row_ptr[n], deg = row_ptr[n + 1] - r0;
    u16* op = &xcat[(size_t)n * 256 + ooff + 2 * lane];
    if (deg == 0) {
        *(u32*)op = 0;
        return;
    }
    float4 ern = er4[n];  // wave-uniform
    float acc0 = 0.f, acc1 = 0.f;
    if (deg <= 64) {
        // lane i owns edge i: coalesced src/w, gathered el
        float4 l = make_float4(-INFINITY, -INFINITY, -INFINITY, -INFINITY);
        int s = 0;
        if (lane < deg) {
            s = src_s[r0 + lane];
            float we = w_s[r0 + lane];
            float4 e = el4[s];
            l.x = we * lrelu(e.x + ern.x);
            l.y = we * lrelu(e.y + ern.y);
            l.z = we * lrelu(e.z + ern.z);
            l.w = we * lrelu(e.w + ern.w);
        }
        float4 mx = l;
        for (int m = 32; m >= 1; m >>= 1) {
            mx.x = fmaxf(mx.x, __shfl_xor(mx.x, m));
            mx.y = fmaxf(mx.y, __shfl_xor(mx.y, m));
            mx.z = fmaxf(mx.z, __shfl_xor(mx.z, m));
            mx.w = fmaxf(mx.w, __shfl_xor(mx.w, m));
        }
        float4 a = make_float4(0.f, 0.f, 0.f, 0.f);
        if (lane < deg) {
            a.x = __expf(l.x - mx.x); a.y = __expf(l.y - mx.y);
            a.z = __expf(l.z - mx.z); a.w = __expf(l.w - mx.w);
        }
        float4 sm = a;
        for (int m = 32; m >= 1; m >>= 1) {
            sm.x += __shfl_xor(sm.x, m);
            sm.y += __shfl_xor(sm.y, m);
            sm.z += __shfl_xor(sm.z, m);
            sm.w += __shfl_xor(sm.w, m);
        }
        a.x = a.x / sm.x; a.y = a.y / sm.y;
        a.z = a.z / sm.z; a.w = a.w / sm.w;
        // stage alpha/src in LDS (per-wave private; DS ops in-order within wave)
        sA[wv * 64 + lane] = a;
        sS[wv * 64 + lane] = s;
        const float* sAf = (const float*)&sA[wv * 64];
        const int* sSp = &sS[wv * 64];
        int i = 0;
        for (; i + 4 <= deg; i += 4) {  // 4 independent gathers in flight
            float w0 = sAf[(i + 0) * 4 + head];
            float w1 = sAf[(i + 1) * 4 + head];
            float w2 = sAf[(i + 2) * 4 + head];
            float w3 = sAf[(i + 3) * 4 + head];
            int s0 = sSp[i + 0], s1 = sSp[i + 1], s2 = sSp[i + 2], s3 = sSp[i + 3];
            u32 p0 = fth2[(size_t)s0 * 64 + lane];
            u32 p1 = fth2[(size_t)s1 * 64 + lane];
            u32 p2 = fth2[(size_t)s2 * 64 + lane];
            u32 p3 = fth2[(size_t)s3 * 64 + lane];
            f16x2 h0 = *(const f16x2*)&p0, h1 = *(const f16x2*)&p1;
            f16x2 h2 = *(const f16x2*)&p2, h3 = *(const f16x2*)&p3;
            acc0 += w0 * (float)h0.x; acc1 += w0 * (float)h0.y;
            acc0 += w1 * (float)h1.x; acc1 += w1 * (float)h1.y;
            acc0 += w2 * (float)h2.x; acc1 += w2 * (float)h2.y;
            acc0 += w3 * (float)h3.x; acc1 += w3 * (float)h3.y;
        }
        for (; i < deg; i++) {
            float wgt = sAf[i * 4 + head];
            int si = sSp[i];
            u32 p = fth2[(size_t)si * 64 + lane];
            f16x2 hp = *(const f16x2*)&p;
            acc0 += wgt * (float)hp.x;
            acc1 += wgt * (float)hp.y;
        }
    } else {
        // fallback for deg > 64 (rare): recompute logits per pass
        float4 mx = make_float4(-INFINITY, -INFINITY, -INFINITY, -INFINITY);
        for (int i = lane; i < deg; i += 64) {
            float we = w_s[r0 + i];
            float4 e = el4[src_s[r0 + i]];
            mx.x = fmaxf(mx.x, we * lrelu(e.x + ern.x));
            mx.y = fmaxf(mx.y, we * lrelu(e.y + ern.y));
            mx.z = fmaxf(mx.z, we * lrelu(e.z + ern.z));
            mx.w = fmaxf(mx.w, we * lrelu(e.w + ern.w));
        }
        for (int m = 32; m >= 1; m >>= 1) {
            mx.x = fmaxf(mx.x, __shfl_xor(mx.x, m));
            mx.y = fmaxf(mx.y, __shfl_xor(mx.y, m));
            mx.z = fmaxf(mx.z, __shfl_xor(mx.z, m));
            mx.w = fmaxf(mx.w, __shfl_xor(mx.w, m));
        }
        float4 sm = make_float4(0.f, 0.f, 0.f, 0.f);
        for (int i = lane; i < deg; i += 64) {
            float we = w_s[r0 + i];
            float4 e = el4[src_s[r0 + i]];
            sm.x += __expf(we * lrelu(e.x + ern.x) - mx.x);
            sm.y += __expf(we * lrelu(e.y + ern.y) - mx.y);
            sm.z += __expf(we * lrelu(e.z + ern.z) - mx.z);
            sm.w += __expf(we * lrelu(e.w + ern.w) - mx.w);
        }
        for (int m = 32; m >= 1; m >>= 1) {
            sm.x += __shfl_xor(sm.x, m);
            sm.y += __shfl_xor(sm.y, m);
            sm.z += __shfl_xor(sm.z, m);
            sm.w += __shfl_xor(sm.w, m);
        }
        float4 inv;
        inv.x = 1.f / sm.x; inv.y = 1.f / sm.y;
        inv.z = 1.f / sm.z; inv.w = 1.f / sm.w;
        for (int i = 0; i < deg; i++) {
            int si = src_s[r0 + i];
            float we = w_s[r0 + i];
            float4 e = el4[si];
            float ax = __expf(we * lrelu(e.x + ern.x) - mx.x) * inv.x;
            float ay = __expf(we * lrelu(e.y + ern.y) - mx.y) * inv.y;
            float az = __expf(we * lrelu(e.z + ern.z) - mx.z) * inv.z;
            float aw = __expf(we * lrelu(e.w + ern.w) - mx.w) * inv.w;
            float wgt = head == 0 ? ax : (head == 1 ? ay : (head == 2 ? az : aw));
            u32 p = fth2[(size_t)si * 64 + lane];
            f16x2 hp = *(const f16x2*)&p;
            acc0 += wgt * (float)hp.x;
            acc1 += wgt * (float)hp.y;
        }
    }
    f16x2 hv;
    hv.x = (f16)fmaxf(acc0, 0.f);
    hv.y = (f16)fmaxf(acc1, 0.f);
    *(f16x2*)op = hv;
}

// ---------------- launch ----------------

extern "C" void kernel_launch(void* const* d_in, const int* in_sizes, int n_in,
                              void* d_out, int out_size, void* d_ws, size_t ws_size,
                              hipStream_t stream) {
    const float* features = (const float*)d_in[0];
    const int* src = (const int*)d_in[1];
    const int* dst = (const int*)d_in[2];
    const float* w = (const float*)d_in[3];
    const float* W1 = (const float*)d_in[4];
    const float* al1 = (const float*)d_in[5];
    const float* ar1 = (const float*)d_in[6];
    const float* W2 = (const float*)d_in[7];
    const float* al2 = (const float*)d_in[8];
    const float* ar2 = (const float*)d_in[9];
    const float* Wout = (const float*)d_in[10];
    const float* bout = (const float*)d_in[11];
    float* out = (float*)d_out;

    int N = in_sizes[0] / 256;           // 50000
    int E = in_sizes[1];                 // 400000
    int Mpad = ((N + 127) / 128) * 128;  // 50048

    char* ws = (char*)d_ws;
    size_t off = 0;
    auto alloc = [&](size_t bytes) -> void* {
        void* p = ws + off;
        off = (off + bytes + 255) & ~(size_t)255;
        return p;
    };
    size_t Nr = ((size_t)N * 4 + 255) & ~(size_t)255;
    int* cnt = (int*)alloc(2 * Nr);                  // cnt + fill contiguous (single memset)
    int* fill = (int*)((char*)cnt + Nr);
    int* row_ptr = (int*)alloc((size_t)(N + 1) * 4);
    int* bsum = (int*)alloc(256 * 4);
    int* boff = (int*)alloc(256 * 4);
    int* src_s = (int*)alloc((size_t)E * 4);
    float* w_s = (float*)alloc((size_t)E * 4);
    u16* fth = (u16*)alloc((size_t)Mpad * 128 * 2);   // fp16 node features (per layer)
    float* el = (float*)alloc((size_t)N * 4 * 4);
    float* er = (float*)alloc((size_t)N * 4 * 4);
    u16* xcat = (u16*)alloc((size_t)Mpad * 256 * 2);  // concat(x1,x2) fp16
    u16* b1 = (u16*)alloc((size_t)256 * 128 * 2);
    u16* b2 = (u16*)alloc((size_t)128 * 128 * 2);
    u16* b3 = (u16*)alloc((size_t)256 * 128 * 2);
    (void)ws_size; (void)n_in; (void)out_size;

    hipMemsetAsync(cnt, 0, 2 * Nr, stream);

    int eb = (E + 255) / 256;
    int nb = (N + 255) / 256;
    int wb = (N + 3) / 4;
    int gb = Mpad / 128;

    // CSR by dst (carrying src/w)
    hist_k<<<eb, 256, 0, stream>>>(dst, cnt, E);
    scan1_k<<<nb, 256, 0, stream>>>(cnt, row_ptr, bsum, N);
    scan2_k<<<1, 256, 0, stream>>>(bsum, boff, nb);
    scan3_k<<<nb, 256, 0, stream>>>(row_ptr, boff, N, E);
    scatter_k<<<eb, 256, 0, stream>>>(src, dst, w, row_ptr, fill, src_s, w_s, E);

    // all three weight panels in one dispatch
    castB3_k<<<160, 256, 0, stream>>>(W1, b1, W2, b2, Wout, b3);

    // layer 1: fth = fp16(features @ W1)
    gemm_h_k<<<gb, 256, 0, stream>>>(features, 0, 256, b1, nullptr, nullptr, fth, N, 256);
    elrh_k<<<wb, 256, 0, stream>>>((const u32*)fth, al1, ar1, el, er, N);
    agg_k<<<wb, 256, 0, stream>>>((const u32*)fth, (const float4*)el, (const float4*)er,
                                  src_s, w_s, row_ptr, xcat, 0, N);

    // layer 2: fth = fp16(x1 @ W2)   (A = xcat cols 0..127 fp16, lda 256)
    gemm_h_k<<<gb, 256, 0, stream>>>(xcat, 1, 256, b2, nullptr, nullptr, fth, N, 128);
    elrh_k<<<wb, 256, 0, stream>>>((const u32*)fth, al2, ar2, el, er, N);
    agg_k<<<wb, 256, 0, stream>>>((const u32*)fth, (const float4*)el, (const float4*)er,
                                  src_s, w_s, row_ptr, xcat, 128, N);

    // output GEMM: out = xcat @ Wout + bout (fp16 A, fp32 out)
    gemm_h_k<<<gb, 256, 0, stream>>>(xcat, 1, 256, b3, bout, out, nullptr, N, 256);
}

// Round 7
// 276.593 us; speedup vs baseline: 2.3003x; 1.1080x over previous
//
#include <hip/hip_runtime.h>
#include <math.h>

#define NHEAD 4
#define HDIM 32
#define NEG_SLOPE 0.1f

typedef unsigned short u16;
typedef unsigned int u32;
typedef _Float16 f16;
typedef f16 f16x2 __attribute__((ext_vector_type(2)));
typedef f16 f16x4 __attribute__((ext_vector_type(4)));
typedef f16 f16x8 __attribute__((ext_vector_type(8)));
typedef float f32x4 __attribute__((ext_vector_type(4)));

// async 16B global->LDS (lds dest = wave-uniform base + lane*16)
#define GLLDS16(g, l) __builtin_amdgcn_global_load_lds( \
    (const __attribute__((address_space(1))) void*)(g), \
    (__attribute__((address_space(3))) void*)(l), 16, 0, 0)

// ---------------- hist + all weight-panel casts in one dispatch ----------------
// Panel layout [kt][n][kk-pair] fp16, NC cols (144 = 128 W-cols + 4 W·al + 4 W·ar + 8 zero).

__device__ __forceinline__ void cast_panel(const float* __restrict__ W,
                                           const float* __restrict__ al,
                                           const float* __restrict__ ar,
                                           u16* __restrict__ bp, int t, int NC) {
    int per_kt = NC * 16;
    int kt = t / per_kt;
    int rem = t - kt * per_kt;
    int n = rem >> 4;
    int kkp = rem & 15;
    int k = kt * 32 + kkp * 2;
    float v0 = 0.f, v1 = 0.f;
    if (n < 128) {
        v0 = W[(size_t)k * 128 + n];
        v1 = W[(size_t)(k + 1) * 128 + n];
    } else if (n < 136) {
        const float* av = (n < 132) ? al : ar;
        int h = (n < 132) ? (n - 128) : (n - 132);
        float s0 = 0.f, s1 = 0.f;
        for (int d = 0; d < 32; d++) {
            float a = av[h * 32 + d];
            s0 += W[(size_t)k * 128 + h * 32 + d] * a;
            s1 += W[(size_t)(k + 1) * 128 + h * 32 + d] * a;
        }
        v0 = s0; v1 = s1;
    }
    f16x2 p;
    p.x = (f16)v0; p.y = (f16)v1;
    *(f16x2*)&((u32*)bp)[t] = p;
}

__global__ void histcast_k(const int* __restrict__ dst, int* __restrict__ cnt, int E,
                           const float* __restrict__ W1, const float* __restrict__ al1,
                           const float* __restrict__ ar1, u16* __restrict__ b1,
                           const float* __restrict__ W2, const float* __restrict__ al2,
                           const float* __restrict__ ar2, u16* __restrict__ b2,
                           const float* __restrict__ W3, u16* __restrict__ b3) {
    int t = blockIdx.x * 256 + threadIdx.x;
    if (t < E) atomicAdd(&cnt[dst[t]], 1);
    // b1: 8 kt * 2304 = 18432 u32; b2: 4 * 2304 = 9216; b3: 8 * 2048 = 16384
    if (t < 18432) cast_panel(W1, al1, ar1, b1, t, 144);
    else if (t < 27648) cast_panel(W2, al2, ar2, b2, t - 18432, 144);
    else if (t < 44032) cast_panel(W3, nullptr, nullptr, b3, t - 27648, 128);
}

// ---------------- segment assignment: start[n] via block scan + one atomic ----------------

__global__ void assign_k(const int* __restrict__ cnt, int* __restrict__ start,
                         int* __restrict__ ctr, int N) {
    __shared__ int s[256];
    __shared__ int base;
    int t = threadIdx.x;
    int i = blockIdx.x * 256 + t;
    int v = (i < N) ? cnt[i] : 0;
    s[t] = v;
    __syncthreads();
    int incl = v;
    for (int off = 1; off < 256; off <<= 1) {
        int add = (t >= off) ? s[t - off] : 0;
        __syncthreads();
        incl += add;
        s[t] = incl;
        __syncthreads();
    }
    if (t == 255) base = atomicAdd(ctr, incl);
    __syncthreads();
    if (i < N) start[i] = base + incl - v;
}

// scatter edges into segments, carrying src and w
__global__ void scatter_k(const int* __restrict__ src, const int* __restrict__ dst,
                          const float* __restrict__ w, const int* __restrict__ start,
                          int* __restrict__ fill, int* __restrict__ src_s,
                          float* __restrict__ w_s, int E) {
    int e = blockIdx.x * 256 + threadIdx.x;
    if (e >= E) return;
    int d = dst[e];
    int p = atomicAdd(&fill[d], 1);
    int idx = start[d] + p;
    src_s[idx] = src[e];
    w_s[idx] = w[e];
}

// ---------------- fp16 MFMA GEMM: C = A[M,K](lda) @ B + bias; NT=9 also emits el/er ----------------
// A fp32 (cvt during staging) or fp16 (async global->LDS). Tile 128x(16*NT), BK=32.

template <int NT>
__global__ __launch_bounds__(256) void gemm_h_k(
        const void* __restrict__ Av, int a_is_f16, int lda,
        const u16* __restrict__ Bp,
        const float* __restrict__ bias, float* __restrict__ Cf,
        u16* __restrict__ Ch, float* __restrict__ el, float* __restrict__ er,
        int M, int K) {
    __shared__ u16 As[4096];
    __shared__ u16 Bs[NT * 512];
    int tid = threadIdx.x;
    int w = tid >> 6, lane = tid & 63;
    int row0 = blockIdx.x * 128;
    int mrow = lane & 15;
    int koff = (lane >> 4) * 8;

    f32x4 acc[2][NT];
#pragma unroll
    for (int mt = 0; mt < 2; mt++)
#pragma unroll
        for (int nt = 0; nt < NT; nt++) acc[mt][nt] = (f32x4){0.f, 0.f, 0.f, 0.f};

    for (int k0 = 0; k0 < K; k0 += 32) {
        int kt = k0 >> 5;
        // B: async global->LDS; NT*64 chunks of 16B, NT*16 per wave
#pragma unroll
        for (int i = 0; i < (NT * 16 + 63) / 64; i++) {
            int ci = i * 64 + lane;
            if (ci < NT * 16) {
                int c = w * (NT * 16) + ci;
                GLLDS16(Bp + (size_t)kt * (NT * 512) + (size_t)c * 8, &Bs[c * 8]);
            }
        }
        if (a_is_f16) {
            const u16* Ah = (const u16*)Av;
#pragma unroll
            for (int i = 0; i < 2; i++) {
                int c = (w * 2 + i) * 64 + lane;
                int r = c >> 2, kk = (c & 3) << 3;
                GLLDS16(Ah + (size_t)(row0 + r) * lda + k0 + kk, &As[c * 8]);
            }
        } else {
            const float* Af = (const float*)Av;
#pragma unroll
            for (int i = 0; i < 4; i++) {
                int flat = tid + i * 256;
                int r = flat >> 3, c4 = flat & 7;
                int row = min(row0 + r, M - 1);  // clamp; pad rows discarded in epilogue
                float4 v = *(const float4*)&Af[(size_t)row * lda + k0 + c4 * 4];
                f16x4 p;
                p.x = (f16)v.x; p.y = (f16)v.y; p.z = (f16)v.z; p.w = (f16)v.w;
                *(f16x4*)&As[r * 32 + c4 * 4] = p;
            }
        }
        __syncthreads();

        f16x8 ah[2];
#pragma unroll
        for (int mt = 0; mt < 2; mt++)
            ah[mt] = *(const f16x8*)&As[(w * 32 + mt * 16 + mrow) * 32 + koff];
#pragma unroll
        for (int nt = 0; nt < NT; nt++) {
            f16x8 bh = *(const f16x8*)&Bs[(nt * 16 + mrow) * 32 + koff];
#pragma unroll
            for (int mt = 0; mt < 2; mt++)
                acc[mt][nt] = __builtin_amdgcn_mfma_f32_16x16x32_f16(ah[mt], bh, acc[mt][nt], 0, 0, 0);
        }
        __syncthreads();
    }

    // epilogue: C/D layout col=lane&15, row=(lane>>4)*4+reg
#pragma unroll
    for (int mt = 0; mt < 2; mt++) {
        int rbase = row0 + w * 32 + mt * 16 + (lane >> 4) * 4;
#pragma unroll
        for (int nt = 0; nt < 8; nt++) {
            int col = nt * 16 + mrow;
            float bv = bias ? bias[col] : 0.f;
            f32x4 v = acc[mt][nt];
#pragma unroll
            for (int reg = 0; reg < 4; reg++) {
                int rr = rbase + reg;
                if (rr < M) {
                    float val = v[reg] + bv;
                    if (Cf) Cf[(size_t)rr * 128 + col] = val;
                    if (Ch) *(f16*)&Ch[(size_t)rr * 128 + col] = (f16)val;
                }
            }
        }
        if (NT == 9) {  // cols 128..135: el heads 0-3, er heads 0-3
            f32x4 v = acc[mt][8];
#pragma unroll
            for (int reg = 0; reg < 4; reg++) {
                int rr = rbase + reg;
                if (rr < M) {
                    if (mrow < 4) el[rr * 4 + mrow] = v[reg];
                    else if (mrow < 8) er[rr * 4 + (mrow - 4)] = v[reg];
                }
            }
        }
    }
}

// ---------------- fused logits + softmax + aggregation ----------------
// lane covers feature dims 2*lane, 2*lane+1; head = lane>>4. Writes fp16 into concat buffer.

__device__ __forceinline__ float lrelu(float x) {
    return x > 0.f ? x : NEG_SLOPE * x;
}

__global__ __launch_bounds__(256) void agg_k(const u32* __restrict__ fth2,
                                             const float4* __restrict__ el4,
                                             const float4* __restrict__ er4,
                                             const int* __restrict__ src_s,
                                             const float* __restrict__ w_s,
                                             const int* __restrict__ start,
                                             const int* __restrict__ cnt,
                                             u16* __restrict__ xcat,
                                             int ooff, int N) {
    __shared__ float4 sA[256];  // [wave*64 + edge] normalized alphas
    __shared__ int sS[256];     // [wave*64 + edge] src node
    int wv = threadIdx.x >> 6;
    int n = blockIdx.x * 4 + wv;
    if (n >= N) return;
    int lane = threadIdx.x & 63;
    int head = lane >> 4;
    int r0 = start[n], deg = cnt[n];
    u16* op = &xcat[(size_t)n * 256 + ooff + 2 * lane];
    if (deg == 0) {
        *(u32*)op = 0;
        return;
    }
    float4 ern = er4[n];  // wave-uniform
    float acc0 = 0.f, acc1 = 0.f;
    if (deg <= 64) {
        // lane i owns edge i. Logits are tiny (|l| < ~2): softmax without max-shift is safe.
        float4 a = make_float4(0.f, 0.f, 0.f, 0.f);
        int s = 0;
        if (lane < deg) {
            s = src_s[r0 + lane];
            float we = w_s[r0 + lane];
            float4 e = el4[s];
            a.x = __expf(we * lrelu(e.x + ern.x));
            a.y = __expf(we * lrelu(e.y + ern.y));
            a.z = __expf(we * lrelu(e.z + ern.z));
            a.w = __expf(we * lrelu(e.w + ern.w));
        }
        float4 sm = a;
        for (int m = 1; m < deg; m <<= 1) {  // truncated butterfly: lanes 0..deg-1 correct
            sm.x += __shfl_xor(sm.x, m);
            sm.y += __shfl_xor(sm.y, m);
            sm.z += __shfl_xor(sm.z, m);
            sm.w += __shfl_xor(sm.w, m);
        }
        a.x = a.x / sm.x; a.y = a.y / sm.y;
        a.z = a.z / sm.z; a.w = a.w / sm.w;
        // stage alpha/src in LDS (per-wave private; DS ops in-order within wave)
        sA[wv * 64 + lane] = a;
        sS[wv * 64 + lane] = s;
        const float* sAf = (const float*)&sA[wv * 64];
        const int* sSp = &sS[wv * 64];
        int i = 0;
        for (; i + 4 <= deg; i += 4) {  // 4 independent gathers in flight
            float w0 = sAf[(i + 0) * 4 + head];
            float w1 = sAf[(i + 1) * 4 + head];
            float w2 = sAf[(i + 2) * 4 + head];
            float w3 = sAf[(i + 3) * 4 + head];
            int s0 = sSp[i + 0], s1 = sSp[i + 1], s2 = sSp[i + 2], s3 = sSp[i + 3];
            u32 p0 = fth2[(size_t)s0 * 64 + lane];
            u32 p1 = fth2[(size_t)s1 * 64 + lane];
            u32 p2 = fth2[(size_t)s2 * 64 + lane];
            u32 p3 = fth2[(size_t)s3 * 64 + lane];
            f16x2 h0 = *(const f16x2*)&p0, h1 = *(const f16x2*)&p1;
            f16x2 h2 = *(const f16x2*)&p2, h3 = *(const f16x2*)&p3;
            acc0 += w0 * (float)h0.x; acc1 += w0 * (float)h0.y;
            acc0 += w1 * (float)h1.x; acc1 += w1 * (float)h1.y;
            acc0 += w2 * (float)h2.x; acc1 += w2 * (float)h2.y;
            acc0 += w3 * (float)h3.x; acc1 += w3 * (float)h3.y;
        }
        for (; i < deg; i++) {
            float wgt = sAf[i * 4 + head];
            int si = sSp[i];
            u32 p = fth2[(size_t)si * 64 + lane];
            f16x2 hp = *(const f16x2*)&p;
            acc0 += wgt * (float)hp.x;
            acc1 += wgt * (float)hp.y;
        }
    } else {
        // fallback for deg > 64 (rare): lane-strided, keep max-shift
        float4 mx = make_float4(-INFINITY, -INFINITY, -INFINITY, -INFINITY);
        for (int i = lane; i < deg; i += 64) {
            float we = w_s[r0 + i];
            float4 e = el4[src_s[r0 + i]];
            mx.x = fmaxf(mx.x, we * lrelu(e.x + ern.x));
            mx.y = fmaxf(mx.y, we * lrelu(e.y + ern.y));
            mx.z = fmaxf(mx.z, we * lrelu(e.z + ern.z));
            mx.w = fmaxf(mx.w, we * lrelu(e.w + ern.w));
        }
        for (int m = 32; m >= 1; m >>= 1) {
            mx.x = fmaxf(mx.x, __shfl_xor(mx.x, m));
            mx.y = fmaxf(mx.y, __shfl_xor(mx.y, m));
            mx.z = fmaxf(mx.z, __shfl_xor(mx.z, m));
            mx.w = fmaxf(mx.w, __shfl_xor(mx.w, m));
        }
        float4 sm = make_float4(0.f, 0.f, 0.f, 0.f);
        for (int i = lane; i < deg; i += 64) {
            float we = w_s[r0 + i];
            float4 e = el4[src_s[r0 + i]];
            sm.x += __expf(we * lrelu(e.x + ern.x) - mx.x);
            sm.y += __expf(we * lrelu(e.y + ern.y) - mx.y);
            sm.z += __expf(we * lrelu(e.z + ern.z) - mx.z);
            sm.w += __expf(we * lrelu(e.w + ern.w) - mx.w);
        }
        for (int m = 32; m >= 1; m >>= 1) {
            sm.x += __shfl_xor(sm.x, m);
            sm.y += __shfl_xor(sm.y, m);
            sm.z += __shfl_xor(sm.z, m);
            sm.w += __shfl_xor(sm.w, m);
        }
        float4 inv;
        inv.x = 1.f / sm.x; inv.y = 1.f / sm.y;
        inv.z = 1.f / sm.z; inv.w = 1.f / sm.w;
        for (int i = 0; i < deg; i++) {
            int si = src_s[r0 + i];
            float we = w_s[r0 + i];
            float4 e = el4[si];
            float ax = __expf(we * lrelu(e.x + ern.x) - mx.x) * inv.x;
            float ay = __expf(we * lrelu(e.y + ern.y) - mx.y) * inv.y;
            float az = __expf(we * lrelu(e.z + ern.z) - mx.z) * inv.z;
            float aw = __expf(we * lrelu(e.w + ern.w) - mx.w) * inv.w;
            float wgt = head == 0 ? ax : (head == 1 ? ay : (head == 2 ? az : aw));
            u32 p = fth2[(size_t)si * 64 + lane];
            f16x2 hp = *(const f16x2*)&p;
            acc0 += wgt * (float)hp.x;
            acc1 += wgt * (float)hp.y;
        }
    }
    f16x2 hv;
    hv.x = (f16)fmaxf(acc0, 0.f);
    hv.y = (f16)fmaxf(acc1, 0.f);
    *(f16x2*)op = hv;
}

// ---------------- launch ----------------

extern "C" void kernel_launch(void* const* d_in, const int* in_sizes, int n_in,
                              void* d_out, int out_size, void* d_ws, size_t ws_size,
                              hipStream_t stream) {
    const float* features = (const float*)d_in[0];
    const int* src = (const int*)d_in[1];
    const int* dst = (const int*)d_in[2];
    const float* w = (const float*)d_in[3];
    const float* W1 = (const float*)d_in[4];
    const float* al1 = (const float*)d_in[5];
    const float* ar1 = (const float*)d_in[6];
    const float* W2 = (const float*)d_in[7];
    const float* al2 = (const float*)d_in[8];
    const float* ar2 = (const float*)d_in[9];
    const float* Wout = (const float*)d_in[10];
    const float* bout = (const float*)d_in[11];
    float* out = (float*)d_out;

    int N = in_sizes[0] / 256;           // 50000
    int E = in_sizes[1];                 // 400000
    int Mpad = ((N + 127) / 128) * 128;  // 50048

    char* ws = (char*)d_ws;
    size_t off = 0;
    auto alloc = [&](size_t bytes) -> void* {
        void* p = ws + off;
        off = (off + bytes + 255) & ~(size_t)255;
        return p;
    };
    size_t Nr = ((size_t)N * 4 + 255) & ~(size_t)255;
    int* cnt = (int*)alloc(2 * Nr + 256);            // cnt + fill + ctr, single memset
    int* fill = (int*)((char*)cnt + Nr);
    int* ctr = (int*)((char*)cnt + 2 * Nr);
    int* start = (int*)alloc((size_t)N * 4);
    int* src_s = (int*)alloc((size_t)E * 4);
    float* w_s = (float*)alloc((size_t)E * 4);
    u16* fth = (u16*)alloc((size_t)Mpad * 128 * 2);   // fp16 node features (per layer)
    float* el = (float*)alloc((size_t)N * 4 * 4);
    float* er = (float*)alloc((size_t)N * 4 * 4);
    u16* xcat = (u16*)alloc((size_t)Mpad * 256 * 2);  // concat(x1,x2) fp16
    u16* b1 = (u16*)alloc((size_t)18432 * 4);         // 144-col panel, K=256
    u16* b2 = (u16*)alloc((size_t)9216 * 4);          // 144-col panel, K=128
    u16* b3 = (u16*)alloc((size_t)16384 * 4);         // 128-col panel, K=256
    (void)ws_size; (void)n_in; (void)out_size;

    hipMemsetAsync(cnt, 0, 2 * Nr + 256, stream);

    int eb = (E + 255) / 256;
    int nb = (N + 255) / 256;
    int wb = (N + 3) / 4;
    int gb = Mpad / 128;

    // CSR-ish build + weight panels
    histcast_k<<<eb, 256, 0, stream>>>(dst, cnt, E, W1, al1, ar1, b1,
                                       W2, al2, ar2, b2, Wout, b3);
    assign_k<<<nb, 256, 0, stream>>>(cnt, start, ctr, N);
    scatter_k<<<eb, 256, 0, stream>>>(src, dst, w, start, fill, src_s, w_s, E);

    // layer 1: fth = fp16(features @ W1), el/er fused as extra B columns
    gemm_h_k<9><<<gb, 256, 0, stream>>>(features, 0, 256, b1, nullptr,
                                        nullptr, fth, el, er, N, 256);
    agg_k<<<wb, 256, 0, stream>>>((const u32*)fth, (const float4*)el, (const float4*)er,
                                  src_s, w_s, start, cnt, xcat, 0, N);

    // layer 2: fth = fp16(x1 @ W2)
    gemm_h_k<9><<<gb, 256, 0, stream>>>(xcat, 1, 256, b2, nullptr,
                                        nullptr, fth, el, er, N, 128);
    agg_k<<<wb, 256, 0, stream>>>((const u32*)fth, (const float4*)el, (const float4*)er,
                                  src_s, w_s, start, cnt, xcat, 128, N);

    // output GEMM: out = xcat @ Wout + bout
    gemm_h_k<8><<<gb, 256, 0, stream>>>(xcat, 1, 256, b3, bout,
                                        out, nullptr, nullptr, nullptr, N, 256);
}

// Round 8
// 259.976 us; speedup vs baseline: 2.4473x; 1.0639x over previous
//
#include <hip/hip_runtime.h>
#include <math.h>

#define NHEAD 4
#define HDIM 32
#define NEG_SLOPE 0.1f

typedef unsigned short u16;
typedef unsigned int u32;
typedef _Float16 f16;
typedef f16 f16x2 __attribute__((ext_vector_type(2)));
typedef f16 f16x4 __attribute__((ext_vector_type(4)));
typedef f16 f16x8 __attribute__((ext_vector_type(8)));
typedef float f32x4 __attribute__((ext_vector_type(4)));

// async 16B global->LDS (lds dest = wave-uniform base + lane*16)
#define GLLDS16(g, l) __builtin_amdgcn_global_load_lds( \
    (const __attribute__((address_space(1))) void*)(g), \
    (__attribute__((address_space(3))) void*)(l), 16, 0, 0)

// ---------------- hist + all weight-panel casts in one dispatch ----------------
// Panel layout [kt][n][kk-pair] fp16, NC cols (144 = 128 W-cols + 4 W·al + 4 W·ar + 8 zero).

__device__ __forceinline__ void cast_panel(const float* __restrict__ W,
                                           const float* __restrict__ al,
                                           const float* __restrict__ ar,
                                           u16* __restrict__ bp, int t, int NC) {
    int per_kt = NC * 16;
    int kt = t / per_kt;
    int rem = t - kt * per_kt;
    int n = rem >> 4;
    int kkp = rem & 15;
    int k = kt * 32 + kkp * 2;
    float v0 = 0.f, v1 = 0.f;
    if (n < 128) {
        v0 = W[(size_t)k * 128 + n];
        v1 = W[(size_t)(k + 1) * 128 + n];
    } else if (n < 136) {
        const float* av = (n < 132) ? al : ar;
        int h = (n < 132) ? (n - 128) : (n - 132);
        float s0 = 0.f, s1 = 0.f;
        for (int d = 0; d < 32; d++) {
            float a = av[h * 32 + d];
            s0 += W[(size_t)k * 128 + h * 32 + d] * a;
            s1 += W[(size_t)(k + 1) * 128 + h * 32 + d] * a;
        }
        v0 = s0; v1 = s1;
    }
    f16x2 p;
    p.x = (f16)v0; p.y = (f16)v1;
    *(f16x2*)&((u32*)bp)[t] = p;
}

__global__ void histcast_k(const int* __restrict__ dst, int* __restrict__ cnt, int E,
                           const float* __restrict__ W1, const float* __restrict__ al1,
                           const float* __restrict__ ar1, u16* __restrict__ b1,
                           const float* __restrict__ W2, const float* __restrict__ al2,
                           const float* __restrict__ ar2, u16* __restrict__ b2,
                           const float* __restrict__ W3, u16* __restrict__ b3) {
    int t = blockIdx.x * 256 + threadIdx.x;
    if (t < E) atomicAdd(&cnt[dst[t]], 1);
    // b1: 8 kt * 2304 = 18432 u32; b2: 4 * 2304 = 9216; b3: 8 * 2048 = 16384
    if (t < 18432) cast_panel(W1, al1, ar1, b1, t, 144);
    else if (t < 27648) cast_panel(W2, al2, ar2, b2, t - 18432, 144);
    else if (t < 44032) cast_panel(W3, nullptr, nullptr, b3, t - 27648, 128);
}

// ---------------- segment assignment: start[n] via block scan + one atomic ----------------

__global__ void assign_k(const int* __restrict__ cnt, int* __restrict__ start,
                         int* __restrict__ ctr, int N) {
    __shared__ int s[256];
    __shared__ int base;
    int t = threadIdx.x;
    int i = blockIdx.x * 256 + t;
    int v = (i < N) ? cnt[i] : 0;
    s[t] = v;
    __syncthreads();
    int incl = v;
    for (int off = 1; off < 256; off <<= 1) {
        int add = (t >= off) ? s[t - off] : 0;
        __syncthreads();
        incl += add;
        s[t] = incl;
        __syncthreads();
    }
    if (t == 255) base = atomicAdd(ctr, incl);
    __syncthreads();
    if (i < N) start[i] = base + incl - v;
}

// scatter edges into segments; (src, w) packed into one int2
__global__ void scatter_k(const int* __restrict__ src, const int* __restrict__ dst,
                          const float* __restrict__ w, const int* __restrict__ start,
                          int* __restrict__ fill, int2* __restrict__ edge_s, int E) {
    int e = blockIdx.x * 256 + threadIdx.x;
    if (e >= E) return;
    int d = dst[e];
    int p = atomicAdd(&fill[d], 1);
    edge_s[start[d] + p] = make_int2(src[e], __float_as_int(w[e]));
}

// ---------------- fp16 MFMA GEMM: C = A[M,K](lda) @ B + bias; NT=9 also emits el/er ----------------
// A fp32 (cvt during staging) or fp16 (async global->LDS). Tile 64x(16*NT), BK=32.
// 64-row tile: acc[9] = 36 VGPRs -> ~4 blocks/CU so inter-block waves hide barrier drains.

template <int NT>
__global__ __launch_bounds__(256) void gemm_h_k(
        const void* __restrict__ Av, int a_is_f16, int lda,
        const u16* __restrict__ Bp,
        const float* __restrict__ bias, float* __restrict__ Cf,
        u16* __restrict__ Ch, float* __restrict__ el, float* __restrict__ er,
        int M, int K) {
    __shared__ u16 As[2048];        // 64 rows x 32 k
    __shared__ u16 Bs[NT * 512];    // NT*16 cols x 32 k
    int tid = threadIdx.x;
    int w = tid >> 6, lane = tid & 63;
    int row0 = blockIdx.x * 64;
    int mrow = lane & 15;
    int koff = (lane >> 4) * 8;

    f32x4 acc[NT];
#pragma unroll
    for (int nt = 0; nt < NT; nt++) acc[nt] = (f32x4){0.f, 0.f, 0.f, 0.f};

    for (int k0 = 0; k0 < K; k0 += 32) {
        int kt = k0 >> 5;
        // B: async global->LDS; NT*64 chunks of 16B across 256 threads
#pragma unroll
        for (int i = 0; i < (NT * 64 + 255) / 256; i++) {
            int c = tid + i * 256;
            if (c < NT * 64)
                GLLDS16(Bp + (size_t)kt * (NT * 512) + (size_t)c * 8, &Bs[c * 8]);
        }
        if (a_is_f16) {
            // A fp16: 256 chunks of 16B, one per thread (r = c>>2, kchunk = c&3)
            const u16* Ah = (const u16*)Av;
            int c = tid;
            int r = c >> 2, kk = (c & 3) << 3;
            GLLDS16(Ah + (size_t)(row0 + r) * lda + k0 + kk, &As[c * 8]);
        } else {
            // A fp32: 512 float4, 2 per thread; cvt to fp16 in regs
            const float* Af = (const float*)Av;
#pragma unroll
            for (int i = 0; i < 2; i++) {
                int flat = tid + i * 256;
                int r = flat >> 3, c4 = flat & 7;
                int row = min(row0 + r, M - 1);  // clamp; pad rows discarded in epilogue
                float4 v = *(const float4*)&Af[(size_t)row * lda + k0 + c4 * 4];
                f16x4 p;
                p.x = (f16)v.x; p.y = (f16)v.y; p.z = (f16)v.z; p.w = (f16)v.w;
                *(f16x4*)&As[r * 32 + c4 * 4] = p;
            }
        }
        __syncthreads();

        f16x8 ah = *(const f16x8*)&As[(w * 16 + mrow) * 32 + koff];
#pragma unroll
        for (int nt = 0; nt < NT; nt++) {
            f16x8 bh = *(const f16x8*)&Bs[(nt * 16 + mrow) * 32 + koff];
            acc[nt] = __builtin_amdgcn_mfma_f32_16x16x32_f16(ah, bh, acc[nt], 0, 0, 0);
        }
        __syncthreads();
    }

    // epilogue: C/D layout col=lane&15, row=(lane>>4)*4+reg
    int rbase = row0 + w * 16 + (lane >> 4) * 4;
#pragma unroll
    for (int nt = 0; nt < 8; nt++) {
        int col = nt * 16 + mrow;
        float bv = bias ? bias[col] : 0.f;
        f32x4 v = acc[nt];
#pragma unroll
        for (int reg = 0; reg < 4; reg++) {
            int rr = rbase + reg;
            if (rr < M) {
                float val = v[reg] + bv;
                if (Cf) Cf[(size_t)rr * 128 + col] = val;
                if (Ch) *(f16*)&Ch[(size_t)rr * 128 + col] = (f16)val;
            }
        }
    }
    if (NT == 9) {  // cols 128..135: el heads 0-3, er heads 0-3
        f32x4 v = acc[8];
#pragma unroll
        for (int reg = 0; reg < 4; reg++) {
            int rr = rbase + reg;
            if (rr < M) {
                if (mrow < 4) el[rr * 4 + mrow] = v[reg];
                else if (mrow < 8) er[rr * 4 + (mrow - 4)] = v[reg];
            }
        }
    }
}

// ---------------- fused logits + softmax + aggregation ----------------
// lane covers feature dims 2*lane, 2*lane+1; head = lane>>4. Writes fp16 into concat buffer.

__device__ __forceinline__ float lrelu(float x) {
    return x > 0.f ? x : NEG_SLOPE * x;
}

__global__ __launch_bounds__(256) void agg_k(const u32* __restrict__ fth2,
                                             const float4* __restrict__ el4,
                                             const float4* __restrict__ er4,
                                             const int2* __restrict__ edge_s,
                                             const int* __restrict__ start,
                                             const int* __restrict__ cnt,
                                             u16* __restrict__ xcat,
                                             int ooff, int N) {
    __shared__ float4 sA[256];  // [wave*64 + edge] normalized alphas
    __shared__ int sS[256];     // [wave*64 + edge] src node
    int wv = threadIdx.x >> 6;
    int n = blockIdx.x * 4 + wv;
    if (n >= N) return;
    int lane = threadIdx.x & 63;
    int head = lane >> 4;
    int r0 = start[n], deg = cnt[n];
    u16* op = &xcat[(size_t)n * 256 + ooff + 2 * lane];
    if (deg == 0) {
        *(u32*)op = 0;
        return;
    }
    float4 ern = er4[n];  // wave-uniform
    float acc0 = 0.f, acc1 = 0.f;
    if (deg <= 64) {
        // lane i owns edge i. Logits are tiny (|l| < ~2): softmax without max-shift is safe.
        float4 a = make_float4(0.f, 0.f, 0.f, 0.f);
        int s = 0;
        if (lane < deg) {
            int2 ep = edge_s[r0 + lane];
            s = ep.x;
            float we = __int_as_float(ep.y);
            float4 e = el4[s];
            a.x = __expf(we * lrelu(e.x + ern.x));
            a.y = __expf(we * lrelu(e.y + ern.y));
            a.z = __expf(we * lrelu(e.z + ern.z));
            a.w = __expf(we * lrelu(e.w + ern.w));
        }
        float4 sm = a;
        for (int m = 1; m < deg; m <<= 1) {  // truncated butterfly: lanes 0..deg-1 correct
            sm.x += __shfl_xor(sm.x, m);
            sm.y += __shfl_xor(sm.y, m);
            sm.z += __shfl_xor(sm.z, m);
            sm.w += __shfl_xor(sm.w, m);
        }
        a.x = a.x / sm.x; a.y = a.y / sm.y;
        a.z = a.z / sm.z; a.w = a.w / sm.w;
        // stage alpha/src in LDS (per-wave private; DS ops in-order within wave)
        sA[wv * 64 + lane] = a;
        sS[wv * 64 + lane] = s;
        const float* sAf = (const float*)&sA[wv * 64];
        const int* sSp = &sS[wv * 64];
        int i = 0;
        for (; i + 8 <= deg; i += 8) {  // 8 independent gathers in flight
            float wg[8];
            u32 pp[8];
#pragma unroll
            for (int j = 0; j < 8; j++) {
                wg[j] = sAf[(i + j) * 4 + head];
                pp[j] = fth2[(size_t)sSp[i + j] * 64 + lane];
            }
#pragma unroll
            for (int j = 0; j < 8; j++) {
                f16x2 hp = *(const f16x2*)&pp[j];
                acc0 += wg[j] * (float)hp.x;
                acc1 += wg[j] * (float)hp.y;
            }
        }
        for (; i < deg; i++) {
            float wgt = sAf[i * 4 + head];
            u32 p = fth2[(size_t)sSp[i] * 64 + lane];
            f16x2 hp = *(const f16x2*)&p;
            acc0 += wgt * (float)hp.x;
            acc1 += wgt * (float)hp.y;
        }
    } else {
        // fallback for deg > 64 (rare): lane-strided, keep max-shift
        float4 mx = make_float4(-INFINITY, -INFINITY, -INFINITY, -INFINITY);
        for (int i = lane; i < deg; i += 64) {
            int2 ep = edge_s[r0 + i];
            float we = __int_as_float(ep.y);
            float4 e = el4[ep.x];
            mx.x = fmaxf(mx.x, we * lrelu(e.x + ern.x));
            mx.y = fmaxf(mx.y, we * lrelu(e.y + ern.y));
            mx.z = fmaxf(mx.z, we * lrelu(e.z + ern.z));
            mx.w = fmaxf(mx.w, we * lrelu(e.w + ern.w));
        }
        for (int m = 32; m >= 1; m >>= 1) {
            mx.x = fmaxf(mx.x, __shfl_xor(mx.x, m));
            mx.y = fmaxf(mx.y, __shfl_xor(mx.y, m));
            mx.z = fmaxf(mx.z, __shfl_xor(mx.z, m));
            mx.w = fmaxf(mx.w, __shfl_xor(mx.w, m));
        }
        float4 sm = make_float4(0.f, 0.f, 0.f, 0.f);
        for (int i = lane; i < deg; i += 64) {
            int2 ep = edge_s[r0 + i];
            float we = __int_as_float(ep.y);
            float4 e = el4[ep.x];
            sm.x += __expf(we * lrelu(e.x + ern.x) - mx.x);
            sm.y += __expf(we * lrelu(e.y + ern.y) - mx.y);
            sm.z += __expf(we * lrelu(e.z + ern.z) - mx.z);
            sm.w += __expf(we * lrelu(e.w + ern.w) - mx.w);
        }
        for (int m = 32; m >= 1; m >>= 1) {
            sm.x += __shfl_xor(sm.x, m);
            sm.y += __shfl_xor(sm.y, m);
            sm.z += __shfl_xor(sm.z, m);
            sm.w += __shfl_xor(sm.w, m);
        }
        float4 inv;
        inv.x = 1.f / sm.x; inv.y = 1.f / sm.y;
        inv.z = 1.f / sm.z; inv.w = 1.f / sm.w;
        for (int i = 0; i < deg; i++) {
            int2 ep = edge_s[r0 + i];
            int si = ep.x;
            float we = __int_as_float(ep.y);
            float4 e = el4[si];
            float ax = __expf(we * lrelu(e.x + ern.x) - mx.x) * inv.x;
            float ay = __expf(we * lrelu(e.y + ern.y) - mx.y) * inv.y;
            float az = __expf(we * lrelu(e.z + ern.z) - mx.z) * inv.z;
            float aw = __expf(we * lrelu(e.w + ern.w) - mx.w) * inv.w;
            float wgt = head == 0 ? ax : (head == 1 ? ay : (head == 2 ? az : aw));
            u32 p = fth2[(size_t)si * 64 + lane];
            f16x2 hp = *(const f16x2*)&p;
            acc0 += wgt * (float)hp.x;
            acc1 += wgt * (float)hp.y;
        }
    }
    f16x2 hv;
    hv.x = (f16)fmaxf(acc0, 0.f);
    hv.y = (f16)fmaxf(acc1, 0.f);
    *(f16x2*)op = hv;
}

// ---------------- launch ----------------

extern "C" void kernel_launch(void* const* d_in, const int* in_sizes, int n_in,
                              void* d_out, int out_size, void* d_ws, size_t ws_size,
                              hipStream_t stream) {
    const float* features = (const float*)d_in[0];
    const int* src = (const int*)d_in[1];
    const int* dst = (const int*)d_in[2];
    const float* w = (const float*)d_in[3];
    const float* W1 = (const float*)d_in[4];
    const float* al1 = (const float*)d_in[5];
    const float* ar1 = (const float*)d_in[6];
    const float* W2 = (const float*)d_in[7];
    const float* al2 = (const float*)d_in[8];
    const float* ar2 = (const float*)d_in[9];
    const float* Wout = (const float*)d_in[10];
    const float* bout = (const float*)d_in[11];
    float* out = (float*)d_out;

    int N = in_sizes[0] / 256;           // 50000
    int E = in_sizes[1];                 // 400000
    int Mpad = ((N + 127) / 128) * 128;  // 50048

    char* ws = (char*)d_ws;
    size_t off = 0;
    auto alloc = [&](size_t bytes) -> void* {
        void* p = ws + off;
        off = (off + bytes + 255) & ~(size_t)255;
        return p;
    };
    size_t Nr = ((size_t)N * 4 + 255) & ~(size_t)255;
    int* cnt = (int*)alloc(2 * Nr + 256);            // cnt + fill + ctr, single memset
    int* fill = (int*)((char*)cnt + Nr);
    int* ctr = (int*)((char*)cnt + 2 * Nr);
    int* start = (int*)alloc((size_t)N * 4);
    int2* edge_s = (int2*)alloc((size_t)E * 8);
    u16* fth = (u16*)alloc((size_t)Mpad * 128 * 2);   // fp16 node features (per layer)
    float* el = (float*)alloc((size_t)N * 4 * 4);
    float* er = (float*)alloc((size_t)N * 4 * 4);
    u16* xcat = (u16*)alloc((size_t)Mpad * 256 * 2);  // concat(x1,x2) fp16
    u16* b1 = (u16*)alloc((size_t)18432 * 4);         // 144-col panel, K=256
    u16* b2 = (u16*)alloc((size_t)9216 * 4);          // 144-col panel, K=128
    u16* b3 = (u16*)alloc((size_t)16384 * 4);         // 128-col panel, K=256
    (void)ws_size; (void)n_in; (void)out_size;

    hipMemsetAsync(cnt, 0, 2 * Nr + 256, stream);

    int eb = (E + 255) / 256;
    int nb = (N + 255) / 256;
    int wb = (N + 3) / 4;
    int gb = Mpad / 64;   // 782 blocks (64-row tiles)

    // CSR-ish build + weight panels
    histcast_k<<<eb, 256, 0, stream>>>(dst, cnt, E, W1, al1, ar1, b1,
                                       W2, al2, ar2, b2, Wout, b3);
    assign_k<<<nb, 256, 0, stream>>>(cnt, start, ctr, N);
    scatter_k<<<eb, 256, 0, stream>>>(src, dst, w, start, fill, edge_s, E);

    // layer 1: fth = fp16(features @ W1), el/er fused as extra B columns
    gemm_h_k<9><<<gb, 256, 0, stream>>>(features, 0, 256, b1, nullptr,
                                        nullptr, fth, el, er, N, 256);
    agg_k<<<wb, 256, 0, stream>>>((const u32*)fth, (const float4*)el, (const float4*)er,
                                  edge_s, start, cnt, xcat, 0, N);

    // layer 2: fth = fp16(x1 @ W2)
    gemm_h_k<9><<<gb, 256, 0, stream>>>(xcat, 1, 256, b2, nullptr,
                                        nullptr, fth, el, er, N, 128);
    agg_k<<<wb, 256, 0, stream>>>((const u32*)fth, (const float4*)el, (const float4*)er,
                                  edge_s, start, cnt, xcat, 128, N);

    // output GEMM: out = xcat @ Wout + bout
    gemm_h_k<8><<<gb, 256, 0, stream>>>(xcat, 1, 256, b3, bout,
                                        out, nullptr, nullptr, nullptr, N, 256);
}